// Round 6
// baseline (779.096 us; speedup 1.0000x reference)
//
#include <hip/hip_runtime.h>
#include <hip/hip_bf16.h>

#define B_ 2048
#define EPSF 1e-5f

typedef __attribute__((ext_vector_type(8))) short short8v;
typedef __attribute__((ext_vector_type(4))) short short4v;
typedef __attribute__((ext_vector_type(4))) float f32x4;

// float -> bf16 bits, round-to-nearest-even
__device__ __forceinline__ short f2bf_s(float f) {
  union { float f; unsigned u; } v; v.f = f;
  unsigned r = v.u + 0x7fffu + ((v.u >> 16) & 1u);
  return (short)(r >> 16);
}
__device__ __forceinline__ float bf2f(short s) {
  return __uint_as_float(((unsigned)(unsigned short)s) << 16);
}

// ---------------- weight prep -------------------------------------------------
// qkvA: [l][3][32][40] bf16 (K=32 pad 40)           7680 shorts
// linb: [l][512][256] bf16                        262144 shorts
// f1wb: [l][128][32] bf16 (packed)                  8192 shorts
// pwb:  [l][128][128] bf16                         32768 shorts
// f2wb: [l][32][128] bf16                           8192 shorts
// convW:[l][9][128] f32 (BN-folded), convB:[l][128] f32
__global__ __launch_bounds__(256) void k_prep(
    const float* __restrict__ f1_w, const float* __restrict__ fpw_w,
    const float* __restrict__ f2_w, const float* __restrict__ qkv_pw,
    const float* __restrict__ lin_w, const float* __restrict__ fdw_w,
    const float* __restrict__ fdw_b, const float* __restrict__ f_bng,
    const float* __restrict__ f_bnb, const float* __restrict__ f_bnm,
    const float* __restrict__ f_bnv, short* __restrict__ qkvA,
    short* __restrict__ linb, short* __restrict__ f1wb,
    short* __restrict__ pwb, short* __restrict__ f2wb,
    float* __restrict__ convW, float* __restrict__ convB) {
  int i = blockIdx.x * 256 + threadIdx.x;
  if (i < 7680) {
    int l = i / 3840, r = i % 3840;
    int io = r / 40, c = r % 40;
    qkvA[i] = (c < 32) ? f2bf_s(qkv_pw[l * 3072 + io * 32 + c]) : (short)0;
  }
  if (i < 262144) linb[i] = f2bf_s(lin_w[i]);
  if (i < 8192) f1wb[i] = f2bf_s(f1_w[i]);
  if (i < 32768) pwb[i] = f2bf_s(fpw_w[i]);
  if (i < 8192) f2wb[i] = f2bf_s(f2_w[i]);
  if (i < 256) {
    int l = i >> 7, c = i & 127;
    float scale = f_bng[l * 128 + c] * rsqrtf(f_bnv[l * 128 + c] + EPSF);
#pragma unroll
    for (int k = 0; k < 9; k++)
      convW[l * 1152 + k * 128 + c] = fdw_w[(l * 128 + c) * 9 + k] * scale;
    convB[l * 128 + c] =
        (fdw_b[l * 128 + c] - f_bnm[l * 128 + c]) * scale + f_bnb[l * 128 + c];
  }
}

// ---------------- shared helper: LN over 512 + to_patches into LDS (fp32) ----
__device__ __forceinline__ void ln_to_patches(const float* __restrict__ xb,
                                              const float* __restrict__ g,
                                              const float* __restrict__ beta,
                                              float (*p)[257], int tid) {
  int lane = tid & 63, wave = tid >> 6;
  for (int r = wave; r < 16; r += 4) {
    float vals[8];
    float s = 0.f, ss = 0.f;
#pragma unroll
    for (int j = 0; j < 8; j++) {
      float t = xb[r * 512 + lane + j * 64];
      vals[j] = t; s += t; ss += t * t;
    }
#pragma unroll
    for (int o = 32; o; o >>= 1) { s += __shfl_xor(s, o); ss += __shfl_xor(ss, o); }
    float m = s * (1.f / 512.f);
    float inv = rsqrtf(ss * (1.f / 512.f) - m * m + EPSF);
#pragma unroll
    for (int j = 0; j < 8; j++) {
      int col = lane + j * 64;
      p[col >> 4][r * 16 + (col & 15)] = (vals[j] - m) * inv * g[col] + beta[col];
    }
  }
}

// ---------------- K_ATT: fused LN1+qkv+attention+c1d+lin+residual ------------
__global__ __launch_bounds__(256) void k_att(
    const float* __restrict__ x, const float* __restrict__ g,
    const float* __restrict__ beta, const float* __restrict__ dw,
    const float* __restrict__ bng, const float* __restrict__ bnb,
    const float* __restrict__ bnm, const float* __restrict__ bnv,
    const short* __restrict__ qkvA, const float* __restrict__ posn,
    const float* __restrict__ c1w, const float* __restrict__ c1b,
    const short* __restrict__ linb, const float* __restrict__ lin_b,
    float* __restrict__ xg) {
  __shared__ __align__(16) char smem[62592];
  float (*p)[257] = (float(*)[257])smem;
  float* sc  = (float*)(smem + 0);
  short* pa  = (short*)(smem + 4224);
  short* ore = (short*)(smem + 6784);
  short* xc1 = (short*)(smem + 11008);
  short* t3s = (short*)(smem + 32896);
  short* qe  = (short*)(smem + 48256);
  short* ke  = (short*)(smem + 52864);
  short* vt  = (short*)(smem + 57472);

  int b = blockIdx.x, tid = threadIdx.x;
  int lane = tid & 63, wid = tid >> 6;
  int row = lane & 15, kg = lane >> 4;
  const float* xb = x + (size_t)b * 8192;

  ln_to_patches(xb, g, beta, p, tid);
  __syncthreads();

  // dw 3x3 s2 + BN (x3) -> t3[i][pos][c]
  {
    int c = tid & 31, oy = tid >> 5;
    float r0[16], r1[16], r2[16];
    int iy0 = 2 * oy - 1;
#pragma unroll
    for (int i = 0; i < 16; i++) {
      r0[i] = (iy0 >= 0) ? p[c][iy0 * 16 + i] : 0.f;
      r1[i] = p[c][(2 * oy) * 16 + i];
      r2[i] = p[c][(2 * oy + 1) * 16 + i];
    }
    for (int iw = 0; iw < 3; iw++) {
      const float* w9 = dw + iw * 288 + c * 9;
      float w00 = w9[0], w01 = w9[1], w02 = w9[2];
      float w10 = w9[3], w11 = w9[4], w12 = w9[5];
      float w20 = w9[6], w21 = w9[7], w22 = w9[8];
      float scale = bng[iw * 32 + c] * rsqrtf(bnv[iw * 32 + c] + EPSF);
      float shift = bnb[iw * 32 + c] - bnm[iw * 32 + c] * scale;
#pragma unroll
      for (int ox = 0; ox < 8; ox++) {
        int ix = 2 * ox;
        float acc = w01 * r0[ix] + w11 * r1[ix] + w21 * r2[ix]
                  + w02 * r0[ix + 1] + w12 * r1[ix + 1] + w22 * r2[ix + 1];
        if (ix > 0) acc += w00 * r0[ix - 1] + w10 * r1[ix - 1] + w20 * r2[ix - 1];
        t3s[(iw * 64 + oy * 8 + ox) * 40 + c] = f2bf_s(acc * scale + shift);
      }
    }
  }
  __syncthreads();

  // pw MFMA -> qe, ke, vt
  {
    int mi = wid & 1, nbase = (wid >> 1) * 2;
    for (int iw = 0; iw < 3; iw++) {
      short8v a = *(const short8v*)&qkvA[(iw * 32 + mi * 16 + row) * 40 + kg * 8];
      short8v b0 = *(const short8v*)&t3s[(iw * 64 + (nbase + 0) * 16 + row) * 40 + kg * 8];
      short8v b1 = *(const short8v*)&t3s[(iw * 64 + (nbase + 1) * 16 + row) * 40 + kg * 8];
      f32x4 z = {};
      f32x4 acc0 = __builtin_amdgcn_mfma_f32_16x16x32_bf16(a, b0, z, 0, 0, 0);
      f32x4 acc1 = __builtin_amdgcn_mfma_f32_16x16x32_bf16(a, b1, z, 0, 0, 0);
      if (iw < 2) {
        short* tgt = (iw == 0) ? qe : ke;
#pragma unroll
        for (int r = 0; r < 4; r++) {
          int d = mi * 16 + kg * 4 + r;
          tgt[d * 72 + (nbase + 0) * 16 + row] = f2bf_s(acc0[r]);
          tgt[d * 72 + (nbase + 1) * 16 + row] = f2bf_s(acc1[r]);
        }
      } else {
        int e0 = (nbase + 0) * 16 + row, e1 = (nbase + 1) * 16 + row;
        int fb = mi * 16 + kg * 4;
        short4v v0, v1;
        v0.x = f2bf_s(acc0[0]); v0.y = f2bf_s(acc0[1]);
        v0.z = f2bf_s(acc0[2]); v0.w = f2bf_s(acc0[3]);
        v1.x = f2bf_s(acc1[0]); v1.y = f2bf_s(acc1[1]);
        v1.z = f2bf_s(acc1[2]); v1.w = f2bf_s(acc1[3]);
        *(short4v*)&vt[e0 * 40 + fb] = v0;
        *(short4v*)&vt[e1 * 40 + fb] = v1;
      }
    }
  }
  __syncthreads();

  // QK^T + position
  {
    int mi = wid & 1, ni = wid >> 1;
    f32x4 acc = {};
#pragma unroll
    for (int kk = 0; kk < 2; kk++) {
      short8v a = *(const short8v*)&qe[(mi * 16 + row) * 72 + kk * 32 + kg * 8];
      short8v bb = *(const short8v*)&ke[(ni * 16 + row) * 72 + kk * 32 + kg * 8];
      acc = __builtin_amdgcn_mfma_f32_16x16x32_bf16(a, bb, acc, 0, 0, 0);
    }
#pragma unroll
    for (int r = 0; r < 4; r++) {
      int d = mi * 16 + kg * 4 + r, f = ni * 16 + row;
      sc[d * 33 + f] = acc[r] * 0.125f + posn[d * 32 + f];
    }
  }
  __syncthreads();

  // softmax
  {
    int srow = tid >> 3, sg = tid & 7;
    float v0 = sc[srow * 33 + sg * 4 + 0];
    float v1 = sc[srow * 33 + sg * 4 + 1];
    float v2 = sc[srow * 33 + sg * 4 + 2];
    float v3 = sc[srow * 33 + sg * 4 + 3];
    float mx = fmaxf(fmaxf(v0, v1), fmaxf(v2, v3));
    mx = fmaxf(mx, __shfl_xor(mx, 1));
    mx = fmaxf(mx, __shfl_xor(mx, 2));
    mx = fmaxf(mx, __shfl_xor(mx, 4));
    float e0 = __expf(v0 - mx), e1 = __expf(v1 - mx);
    float e2 = __expf(v2 - mx), e3 = __expf(v3 - mx);
    float s = e0 + e1 + e2 + e3;
    s += __shfl_xor(s, 1); s += __shfl_xor(s, 2); s += __shfl_xor(s, 4);
    float inv = 1.f / s;
    short4v pk;
    pk.x = f2bf_s(e0 * inv); pk.y = f2bf_s(e1 * inv);
    pk.z = f2bf_s(e2 * inv); pk.w = f2bf_s(e3 * inv);
    *(short4v*)&pa[srow * 40 + sg * 4] = pk;
  }
  __syncthreads();

  // PV
  {
    int mi = wid & 1, nbase = (wid >> 1) * 2;
    short8v a = *(const short8v*)&pa[(mi * 16 + row) * 40 + kg * 8];
#pragma unroll
    for (int t = 0; t < 2; t++) {
      int e = (nbase + t) * 16 + row;
      short8v bb = *(const short8v*)&vt[e * 40 + kg * 8];
      f32x4 z = {};
      f32x4 acc = __builtin_amdgcn_mfma_f32_16x16x32_bf16(a, bb, z, 0, 0, 0);
#pragma unroll
      for (int r = 0; r < 4; r++) {
        int d = mi * 16 + kg * 4 + r;
        ore[(e >> 3) * 264 + d * 8 + (e & 7)] = f2bf_s(acc[r]);
      }
    }
  }
  __syncthreads();

  // c1d
  {
    int n = tid;
#pragma unroll
    for (int u = 0; u < 16; u++) {
      float acc = c1b[u];
#pragma unroll
      for (int c = 0; c < 8; c++)
        acc += c1w[u * 8 + c] * bf2f(ore[c * 264 + n]);
      xc1[u * 264 + n] = f2bf_s(acc);
    }
  }
  __syncthreads();

  // lin MFMA + residual
  {
    short8v a8[8];
#pragma unroll
    for (int kk = 0; kk < 8; kk++)
      a8[kk] = *(const short8v*)&xc1[row * 264 + kk * 32 + kg * 8];
    float* xo = xg + (size_t)b * 8192;
    for (int t = 0; t < 8; t++) {
      int nt = wid * 8 + t;
      const short* bb_base = linb + (nt * 16 + row) * 256 + kg * 8;
      f32x4 acc = {};
#pragma unroll
      for (int kk = 0; kk < 8; kk++) {
        short8v bb = *(const short8v*)(bb_base + kk * 32);
        acc = __builtin_amdgcn_mfma_f32_16x16x32_bf16(a8[kk], bb, acc, 0, 0, 0);
      }
      int m = nt * 16 + row;
      float lb = lin_b[m];
#pragma unroll
      for (int r = 0; r < 4; r++) {
        int u = kg * 4 + r;
        xo[u * 512 + m] += acc[r] + lb;
      }
    }
  }
}

// ---------------- K_FFN3: pos-split, 2 blocks/CU -----------------------------
// LDS (71680 B):
//   sY [128 c][152] bf16  @ 0       (38912 B)  conv input rows of this half
//   sT region @ 38912     (32768 B):
//     - p [256 pos][32] bf16 (LN patches; stashed to regs, restored per half)
//     - conv out [128 pos][128 c] bf16, XOR-swizzled (byte ^= (pos&7)<<4)
//     - r (fpw out) [128 pos][128 o] bf16, same swizzle
__global__ __launch_bounds__(512, 4) void k_ffn3(
    const float* __restrict__ x, const float* __restrict__ g,
    const float* __restrict__ beta, const short* __restrict__ f1wg,
    const float* __restrict__ f1b, const float* __restrict__ convW,
    const float* __restrict__ convB, const short* __restrict__ pwg,
    const float* __restrict__ pwbias, const short* __restrict__ f2wg,
    const float* __restrict__ f2b, float* __restrict__ xg) {
  __shared__ __align__(16) char smem[71680];
  short* sY = (short*)smem;              // [128][152]
  char* sTB = smem + 38912;              // swizzled [128][128] bf16
  short* pP = (short*)(smem + 38912);    // p [256][32]

  int b = blockIdx.x, tid = threadIdx.x;
  int lane = tid & 63, wid = tid >> 6;
  int row = lane & 15, kg = lane >> 4;
  const float* xb = x + (size_t)b * 8192;
  float* xo = xg + (size_t)b * 8192;

  // ---- LN2 -> p ----
  for (int rr = wid; rr < 16; rr += 8) {
    float vals[8];
    float s = 0.f, ss = 0.f;
#pragma unroll
    for (int j = 0; j < 8; j++) {
      float t = xb[rr * 512 + lane + j * 64];
      vals[j] = t; s += t; ss += t * t;
    }
#pragma unroll
    for (int o = 32; o; o >>= 1) { s += __shfl_xor(s, o); ss += __shfl_xor(ss, o); }
    float m = s * (1.f / 512.f);
    float inv = rsqrtf(ss * (1.f / 512.f) - m * m + EPSF);
#pragma unroll
    for (int j = 0; j < 8; j++) {
      int col = lane + j * 64;
      float nv = (vals[j] - m) * inv * g[col] + beta[col];
      pP[(rr * 16 + (col & 15)) * 32 + (col >> 4)] = f2bf_s(nv);
    }
  }
  __syncthreads();
  // stash p (16 shorts/thread)
  uint4 st0 = ((const uint4*)pP)[2 * tid];
  uint4 st1 = ((const uint4*)pP)[2 * tid + 1];

  for (int ph = 0; ph < 2; ++ph) {
    if (ph) {
      __syncthreads();                       // f2 of half0 done reading r
      ((uint4*)pP)[2 * tid] = st0;
      ((uint4*)pP)[2 * tid + 1] = st1;
    }
    __syncthreads();

    // ---- f1 MFMA: y1 rows (9-row halo span) -> sY ----
    {
      int o0 = (wid & 1) * 64;
      for (int tt = (wid >> 1); tt < 9; tt += 4) {
        int rg = (ph ? 7 : 0) + tt;          // global patch row
        short8v bb = *(const short8v*)&pP[(rg * 16 + row) * 32 + kg * 8];
        short8v a0 = *(const short8v*)&f1wg[(o0 + 0 * 16 + row) * 32 + kg * 8];
        short8v a1 = *(const short8v*)&f1wg[(o0 + 1 * 16 + row) * 32 + kg * 8];
        short8v a2 = *(const short8v*)&f1wg[(o0 + 2 * 16 + row) * 32 + kg * 8];
        short8v a3 = *(const short8v*)&f1wg[(o0 + 3 * 16 + row) * 32 + kg * 8];
        f32x4 z = {};
        f32x4 c0 = __builtin_amdgcn_mfma_f32_16x16x32_bf16(a0, bb, z, 0, 0, 0);
        f32x4 c1 = __builtin_amdgcn_mfma_f32_16x16x32_bf16(a1, bb, z, 0, 0, 0);
        f32x4 c2 = __builtin_amdgcn_mfma_f32_16x16x32_bf16(a2, bb, z, 0, 0, 0);
        f32x4 c3 = __builtin_amdgcn_mfma_f32_16x16x32_bf16(a3, bb, z, 0, 0, 0);
#pragma unroll
        for (int mi = 0; mi < 4; mi++) {
          f32x4 cc = (mi == 0) ? c0 : (mi == 1) ? c1 : (mi == 2) ? c2 : c3;
          int ob = o0 + mi * 16 + kg * 4;
#pragma unroll
          for (int r2 = 0; r2 < 4; r2++) {
            int c = ob + r2;
            sY[c * 152 + tt * 16 + row] = f2bf_s(fmaxf(cc[r2] + f1b[c], 0.f));
          }
        }
      }
    }
    __syncthreads();

    // ---- depthwise 3x3 s1 (+folded BN) -> sT swizzled [pos][c] ----
    {
      int c = tid & 127, hb = tid >> 7;      // 2 output rows per thread
      float w_[9];
#pragma unroll
      for (int k = 0; k < 9; k++) w_[k] = convW[k * 128 + c];
      float cb = convB[c];
      int rlo = ph ? 7 : 0;
#pragma unroll
      for (int j = 0; j < 2; j++) {
        int hl = hb * 2 + j;                 // local out row 0..7
        int h = ph * 8 + hl;
        float acc[16];
#pragma unroll
        for (int w = 0; w < 16; w++) acc[w] = cb;
#pragma unroll
        for (int rr = 0; rr < 3; rr++) {
          int rg = h - 1 + rr;
          if (rg < 0 || rg > 15) continue;
          int rl = rg - rlo;
          short8v s0 = *(const short8v*)&sY[c * 152 + rl * 16];
          short8v s1 = *(const short8v*)&sY[c * 152 + rl * 16 + 8];
          float f[18];
          f[0] = 0.f; f[17] = 0.f;
#pragma unroll
          for (int i = 0; i < 8; i++) { f[1 + i] = bf2f(s0[i]); f[9 + i] = bf2f(s1[i]); }
          float w0 = w_[rr * 3], w1 = w_[rr * 3 + 1], w2 = w_[rr * 3 + 2];
#pragma unroll
          for (int w = 0; w < 16; w++)
            acc[w] += w0 * f[w] + w1 * f[w + 1] + w2 * f[w + 2];
        }
#pragma unroll
        for (int w = 0; w < 16; w++) {
          int pos = hl * 16 + w;
          int byte = ((pos * 128 + c) * 2) ^ ((pos & 7) << 4);
          *(short*)(sTB + byte) = f2bf_s(acc[w]);
        }
      }
    }
    __syncthreads();

    // ---- fpw MFMA: [128 o][128 pos], K=128 ----
    int o0 = (wid & 3) * 32, pos0 = (wid >> 2) * 64;
    f32x4 facc[2][4] = {};
#pragma unroll
    for (int kk = 0; kk < 4; kk++) {
      short8v a0 = *(const short8v*)&pwg[(o0 + row) * 128 + kk * 32 + kg * 8];
      short8v a1 = *(const short8v*)&pwg[(o0 + 16 + row) * 128 + kk * 32 + kg * 8];
      short8v bb[4];
#pragma unroll
      for (int ni = 0; ni < 4; ni++) {
        int pos = pos0 + ni * 16 + row;
        int byte = ((pos * 128 + kk * 32 + kg * 8) * 2) ^ ((pos & 7) << 4);
        bb[ni] = *(const short8v*)(sTB + byte);
      }
#pragma unroll
      for (int ni = 0; ni < 4; ni++) {
        facc[0][ni] = __builtin_amdgcn_mfma_f32_16x16x32_bf16(a0, bb[ni], facc[0][ni], 0, 0, 0);
        facc[1][ni] = __builtin_amdgcn_mfma_f32_16x16x32_bf16(a1, bb[ni], facc[1][ni], 0, 0, 0);
      }
    }
    __syncthreads();

    // ---- bias + ReLU -> r (overwrite sT, same swizzle) ----
#pragma unroll
    for (int mi = 0; mi < 2; mi++) {
      int ob = o0 + mi * 16 + kg * 4;
      float pb0 = pwbias[ob], pb1 = pwbias[ob + 1];
      float pb2 = pwbias[ob + 2], pb3 = pwbias[ob + 3];
#pragma unroll
      for (int ni = 0; ni < 4; ni++) {
        int pos = pos0 + ni * 16 + row;
        short4v pk;
        pk.x = f2bf_s(fmaxf(facc[mi][ni][0] + pb0, 0.f));
        pk.y = f2bf_s(fmaxf(facc[mi][ni][1] + pb1, 0.f));
        pk.z = f2bf_s(fmaxf(facc[mi][ni][2] + pb2, 0.f));
        pk.w = f2bf_s(fmaxf(facc[mi][ni][3] + pb3, 0.f));
        int byte = ((pos * 128 + ob) * 2) ^ ((pos & 7) << 4);
        *(short4v*)(sTB + byte) = pk;
      }
    }
    __syncthreads();

    // ---- f2 MFMA: [32 d][128 pos], K=128 + direct residual ----
    {
      f32x4 acc2[2] = {};
      int pos0f = wid * 16;
      int pos = pos0f + row;
#pragma unroll
      for (int kk = 0; kk < 4; kk++) {
        short8v a0 = *(const short8v*)&f2wg[(row) * 128 + kk * 32 + kg * 8];
        short8v a1 = *(const short8v*)&f2wg[(16 + row) * 128 + kk * 32 + kg * 8];
        int byte = ((pos * 128 + kk * 32 + kg * 8) * 2) ^ ((pos & 7) << 4);
        short8v bb = *(const short8v*)(sTB + byte);
        acc2[0] = __builtin_amdgcn_mfma_f32_16x16x32_bf16(a0, bb, acc2[0], 0, 0, 0);
        acc2[1] = __builtin_amdgcn_mfma_f32_16x16x32_bf16(a1, bb, acc2[1], 0, 0, 0);
      }
      int pos_g = ph * 128 + pos;
      int p1 = pos_g >> 4, p2 = pos_g & 15;
#pragma unroll
      for (int mi = 0; mi < 2; mi++)
#pragma unroll
        for (int r2 = 0; r2 < 4; r2++) {
          int d = mi * 16 + kg * 4 + r2;
          xo[p1 * 512 + d * 16 + p2] += acc2[mi][r2] + f2b[d];
        }
    }
  }
}

extern "C" void kernel_launch(void* const* d_in, const int* in_sizes, int n_in,
                              void* d_out, int out_size, void* d_ws, size_t ws_size,
                              hipStream_t stream) {
  const float* x_in   = (const float*)d_in[0];
  const float* ln1_g  = (const float*)d_in[1];
  const float* ln1_b  = (const float*)d_in[2];
  const float* ln2_g  = (const float*)d_in[3];
  const float* ln2_b  = (const float*)d_in[4];
  const float* qkv_dw = (const float*)d_in[5];
  const float* qkv_bng = (const float*)d_in[6];
  const float* qkv_bnb = (const float*)d_in[7];
  const float* qkv_bnm = (const float*)d_in[8];
  const float* qkv_bnv = (const float*)d_in[9];
  const float* qkv_pw = (const float*)d_in[10];
  const float* position = (const float*)d_in[11];
  const float* c1d_w  = (const float*)d_in[12];
  const float* c1d_b  = (const float*)d_in[13];
  const float* lin_w  = (const float*)d_in[14];
  const float* lin_b  = (const float*)d_in[15];
  const float* f1_w   = (const float*)d_in[16];
  const float* f1_b   = (const float*)d_in[17];
  const float* fdw_w  = (const float*)d_in[18];
  const float* fdw_b  = (const float*)d_in[19];
  const float* f_bng  = (const float*)d_in[20];
  const float* f_bnb  = (const float*)d_in[21];
  const float* f_bnm  = (const float*)d_in[22];
  const float* f_bnv  = (const float*)d_in[23];
  const float* fpw_w  = (const float*)d_in[24];
  const float* fpw_b  = (const float*)d_in[25];
  const float* f2_w   = (const float*)d_in[26];
  const float* f2_b   = (const float*)d_in[27];

  float* xbuf = (float*)d_out;                 // running x lives in d_out
  short* qkvA = (short*)d_ws;                  // 7680
  short* linb = qkvA + 7680;                   // 262144
  short* f1wb = linb + 262144;                 // 8192
  short* pwb  = f1wb + 8192;                   // 32768
  short* f2wb = pwb + 32768;                   // 8192
  float* convW = (float*)(f2wb + 8192);        // 2304
  float* convB = convW + 2304;                 // 256

  hipMemcpyAsync(xbuf, x_in, (size_t)B_ * 8192 * sizeof(float),
                 hipMemcpyDeviceToDevice, stream);
  k_prep<<<1024, 256, 0, stream>>>(f1_w, fpw_w, f2_w, qkv_pw, lin_w,
      fdw_w, fdw_b, f_bng, f_bnb, f_bnm, f_bnv,
      qkvA, linb, f1wb, pwb, f2wb, convW, convB);
  for (int l = 0; l < 2; l++) {
    k_att<<<B_, 256, 0, stream>>>(xbuf, ln1_g + l * 512, ln1_b + l * 512,
        qkv_dw + l * 864, qkv_bng + l * 96, qkv_bnb + l * 96,
        qkv_bnm + l * 96, qkv_bnv + l * 96, qkvA + l * 3840,
        position + l * 1024, c1d_w + l * 128, c1d_b + l * 16,
        linb + l * 131072, lin_b + l * 512, xbuf);
    k_ffn3<<<B_, 512, 0, stream>>>(xbuf, ln2_g + l * 512, ln2_b + l * 512,
        f1wb + l * 4096, f1_b + l * 128, convW + l * 1152, convB + l * 128,
        pwb + l * 16384, fpw_b + l * 128, f2wb + l * 4096, f2_b + l * 32, xbuf);
  }
}

// Round 7
// 423.224 us; speedup vs baseline: 1.8409x; 1.8409x over previous
//
#include <hip/hip_runtime.h>
#include <hip/hip_bf16.h>

#define B_ 2048
#define EPSF 1e-5f

typedef __attribute__((ext_vector_type(8))) short short8v;
typedef __attribute__((ext_vector_type(4))) short short4v;
typedef __attribute__((ext_vector_type(4))) float f32x4;

// float -> bf16 bits, round-to-nearest-even
__device__ __forceinline__ short f2bf_s(float f) {
  union { float f; unsigned u; } v; v.f = f;
  unsigned r = v.u + 0x7fffu + ((v.u >> 16) & 1u);
  return (short)(r >> 16);
}
__device__ __forceinline__ float bf2f(short s) {
  return __uint_as_float(((unsigned)(unsigned short)s) << 16);
}

// ---------------- weight prep -------------------------------------------------
// qkvA: [l][3][32][40] bf16                          7680 shorts
// linb: [l][512][256] bf16                         262144 shorts
// f1wb: [l][128][40] bf16 (K=32 pad 40)             10240 shorts
// img:  [l][ pw 128x152 | f2 32x152 ] bf16          48640 shorts
// convW:[l][9][128] f32 (BN-folded), convB:[l][128] f32
__global__ __launch_bounds__(256) void k_prep(
    const float* __restrict__ f1_w, const float* __restrict__ fpw_w,
    const float* __restrict__ f2_w, const float* __restrict__ qkv_pw,
    const float* __restrict__ lin_w, const float* __restrict__ fdw_w,
    const float* __restrict__ fdw_b, const float* __restrict__ f_bng,
    const float* __restrict__ f_bnb, const float* __restrict__ f_bnm,
    const float* __restrict__ f_bnv, short* __restrict__ qkvA,
    short* __restrict__ linb, short* __restrict__ f1wb,
    short* __restrict__ img, float* __restrict__ convW,
    float* __restrict__ convB) {
  int i = blockIdx.x * 256 + threadIdx.x;
  if (i < 7680) {
    int l = i / 3840, r = i % 3840;
    int io = r / 40, c = r % 40;
    qkvA[i] = (c < 32) ? f2bf_s(qkv_pw[l * 3072 + io * 32 + c]) : (short)0;
  }
  if (i < 262144) linb[i] = f2bf_s(lin_w[i]);
  if (i < 10240) {
    int l = i / 5120, r = i % 5120, o = r / 40, kk = r % 40;
    f1wb[i] = (kk < 32) ? f2bf_s(f1_w[l * 4096 + o * 32 + kk]) : (short)0;
  }
  if (i < 48640) {
    int l = i / 24320, r = i % 24320;
    short val;
    if (r < 19456) {
      int o = r / 152, kk = r % 152;
      val = (kk < 128) ? f2bf_s(fpw_w[l * 16384 + o * 128 + kk]) : (short)0;
    } else {
      int r2 = r - 19456;
      int d = r2 / 152, kk = r2 % 152;
      val = (kk < 128) ? f2bf_s(f2_w[l * 4096 + d * 128 + kk]) : (short)0;
    }
    img[i] = val;
  }
  if (i < 256) {
    int l = i >> 7, c = i & 127;
    float scale = f_bng[l * 128 + c] * rsqrtf(f_bnv[l * 128 + c] + EPSF);
#pragma unroll
    for (int k = 0; k < 9; k++)
      convW[l * 1152 + k * 128 + c] = fdw_w[(l * 128 + c) * 9 + k] * scale;
    convB[l * 128 + c] =
        (fdw_b[l * 128 + c] - f_bnm[l * 128 + c]) * scale + f_bnb[l * 128 + c];
  }
}

// ---------------- shared helper: LN over 512 + to_patches into LDS (fp32) ----
__device__ __forceinline__ void ln_to_patches(const float* __restrict__ xb,
                                              const float* __restrict__ g,
                                              const float* __restrict__ beta,
                                              float (*p)[257], int tid) {
  int lane = tid & 63, wave = tid >> 6;
  for (int r = wave; r < 16; r += 4) {
    float vals[8];
    float s = 0.f, ss = 0.f;
#pragma unroll
    for (int j = 0; j < 8; j++) {
      float t = xb[r * 512 + lane + j * 64];
      vals[j] = t; s += t; ss += t * t;
    }
#pragma unroll
    for (int o = 32; o; o >>= 1) { s += __shfl_xor(s, o); ss += __shfl_xor(ss, o); }
    float m = s * (1.f / 512.f);
    float inv = rsqrtf(ss * (1.f / 512.f) - m * m + EPSF);
#pragma unroll
    for (int j = 0; j < 8; j++) {
      int col = lane + j * 64;
      p[col >> 4][r * 16 + (col & 15)] = (vals[j] - m) * inv * g[col] + beta[col];
    }
  }
}

// ---------------- K_ATT: fused LN1+qkv+attention+c1d+lin+residual ------------
__global__ __launch_bounds__(256) void k_att(
    const float* __restrict__ x, const float* __restrict__ g,
    const float* __restrict__ beta, const float* __restrict__ dw,
    const float* __restrict__ bng, const float* __restrict__ bnb,
    const float* __restrict__ bnm, const float* __restrict__ bnv,
    const short* __restrict__ qkvA, const float* __restrict__ posn,
    const float* __restrict__ c1w, const float* __restrict__ c1b,
    const short* __restrict__ linb, const float* __restrict__ lin_b,
    float* __restrict__ xg) {
  __shared__ __align__(16) char smem[62592];
  float (*p)[257] = (float(*)[257])smem;
  float* sc  = (float*)(smem + 0);
  short* pa  = (short*)(smem + 4224);
  short* ore = (short*)(smem + 6784);
  short* xc1 = (short*)(smem + 11008);
  short* t3s = (short*)(smem + 32896);
  short* qe  = (short*)(smem + 48256);
  short* ke  = (short*)(smem + 52864);
  short* vt  = (short*)(smem + 57472);

  int b = blockIdx.x, tid = threadIdx.x;
  int lane = tid & 63, wid = tid >> 6;
  int row = lane & 15, kg = lane >> 4;
  const float* xb = x + (size_t)b * 8192;

  ln_to_patches(xb, g, beta, p, tid);
  __syncthreads();

  // dw 3x3 s2 + BN (x3) -> t3[i][pos][c]
  {
    int c = tid & 31, oy = tid >> 5;
    float r0[16], r1[16], r2[16];
    int iy0 = 2 * oy - 1;
#pragma unroll
    for (int i = 0; i < 16; i++) {
      r0[i] = (iy0 >= 0) ? p[c][iy0 * 16 + i] : 0.f;
      r1[i] = p[c][(2 * oy) * 16 + i];
      r2[i] = p[c][(2 * oy + 1) * 16 + i];
    }
    for (int iw = 0; iw < 3; iw++) {
      const float* w9 = dw + iw * 288 + c * 9;
      float w00 = w9[0], w01 = w9[1], w02 = w9[2];
      float w10 = w9[3], w11 = w9[4], w12 = w9[5];
      float w20 = w9[6], w21 = w9[7], w22 = w9[8];
      float scale = bng[iw * 32 + c] * rsqrtf(bnv[iw * 32 + c] + EPSF);
      float shift = bnb[iw * 32 + c] - bnm[iw * 32 + c] * scale;
#pragma unroll
      for (int ox = 0; ox < 8; ox++) {
        int ix = 2 * ox;
        float acc = w01 * r0[ix] + w11 * r1[ix] + w21 * r2[ix]
                  + w02 * r0[ix + 1] + w12 * r1[ix + 1] + w22 * r2[ix + 1];
        if (ix > 0) acc += w00 * r0[ix - 1] + w10 * r1[ix - 1] + w20 * r2[ix - 1];
        t3s[(iw * 64 + oy * 8 + ox) * 40 + c] = f2bf_s(acc * scale + shift);
      }
    }
  }
  __syncthreads();

  // pw MFMA -> qe, ke, vt
  {
    int mi = wid & 1, nbase = (wid >> 1) * 2;
    for (int iw = 0; iw < 3; iw++) {
      short8v a = *(const short8v*)&qkvA[(iw * 32 + mi * 16 + row) * 40 + kg * 8];
      short8v b0 = *(const short8v*)&t3s[(iw * 64 + (nbase + 0) * 16 + row) * 40 + kg * 8];
      short8v b1 = *(const short8v*)&t3s[(iw * 64 + (nbase + 1) * 16 + row) * 40 + kg * 8];
      f32x4 z = {};
      f32x4 acc0 = __builtin_amdgcn_mfma_f32_16x16x32_bf16(a, b0, z, 0, 0, 0);
      f32x4 acc1 = __builtin_amdgcn_mfma_f32_16x16x32_bf16(a, b1, z, 0, 0, 0);
      if (iw < 2) {
        short* tgt = (iw == 0) ? qe : ke;
#pragma unroll
        for (int r = 0; r < 4; r++) {
          int d = mi * 16 + kg * 4 + r;
          tgt[d * 72 + (nbase + 0) * 16 + row] = f2bf_s(acc0[r]);
          tgt[d * 72 + (nbase + 1) * 16 + row] = f2bf_s(acc1[r]);
        }
      } else {
        int e0 = (nbase + 0) * 16 + row, e1 = (nbase + 1) * 16 + row;
        int fb = mi * 16 + kg * 4;
        short4v v0, v1;
        v0.x = f2bf_s(acc0[0]); v0.y = f2bf_s(acc0[1]);
        v0.z = f2bf_s(acc0[2]); v0.w = f2bf_s(acc0[3]);
        v1.x = f2bf_s(acc1[0]); v1.y = f2bf_s(acc1[1]);
        v1.z = f2bf_s(acc1[2]); v1.w = f2bf_s(acc1[3]);
        *(short4v*)&vt[e0 * 40 + fb] = v0;
        *(short4v*)&vt[e1 * 40 + fb] = v1;
      }
    }
  }
  __syncthreads();

  // QK^T + position
  {
    int mi = wid & 1, ni = wid >> 1;
    f32x4 acc = {};
#pragma unroll
    for (int kk = 0; kk < 2; kk++) {
      short8v a = *(const short8v*)&qe[(mi * 16 + row) * 72 + kk * 32 + kg * 8];
      short8v bb = *(const short8v*)&ke[(ni * 16 + row) * 72 + kk * 32 + kg * 8];
      acc = __builtin_amdgcn_mfma_f32_16x16x32_bf16(a, bb, acc, 0, 0, 0);
    }
#pragma unroll
    for (int r = 0; r < 4; r++) {
      int d = mi * 16 + kg * 4 + r, f = ni * 16 + row;
      sc[d * 33 + f] = acc[r] * 0.125f + posn[d * 32 + f];
    }
  }
  __syncthreads();

  // softmax
  {
    int srow = tid >> 3, sg = tid & 7;
    float v0 = sc[srow * 33 + sg * 4 + 0];
    float v1 = sc[srow * 33 + sg * 4 + 1];
    float v2 = sc[srow * 33 + sg * 4 + 2];
    float v3 = sc[srow * 33 + sg * 4 + 3];
    float mx = fmaxf(fmaxf(v0, v1), fmaxf(v2, v3));
    mx = fmaxf(mx, __shfl_xor(mx, 1));
    mx = fmaxf(mx, __shfl_xor(mx, 2));
    mx = fmaxf(mx, __shfl_xor(mx, 4));
    float e0 = __expf(v0 - mx), e1 = __expf(v1 - mx);
    float e2 = __expf(v2 - mx), e3 = __expf(v3 - mx);
    float s = e0 + e1 + e2 + e3;
    s += __shfl_xor(s, 1); s += __shfl_xor(s, 2); s += __shfl_xor(s, 4);
    float inv = 1.f / s;
    short4v pk;
    pk.x = f2bf_s(e0 * inv); pk.y = f2bf_s(e1 * inv);
    pk.z = f2bf_s(e2 * inv); pk.w = f2bf_s(e3 * inv);
    *(short4v*)&pa[srow * 40 + sg * 4] = pk;
  }
  __syncthreads();

  // PV
  {
    int mi = wid & 1, nbase = (wid >> 1) * 2;
    short8v a = *(const short8v*)&pa[(mi * 16 + row) * 40 + kg * 8];
#pragma unroll
    for (int t = 0; t < 2; t++) {
      int e = (nbase + t) * 16 + row;
      short8v bb = *(const short8v*)&vt[e * 40 + kg * 8];
      f32x4 z = {};
      f32x4 acc = __builtin_amdgcn_mfma_f32_16x16x32_bf16(a, bb, z, 0, 0, 0);
#pragma unroll
      for (int r = 0; r < 4; r++) {
        int d = mi * 16 + kg * 4 + r;
        ore[(e >> 3) * 264 + d * 8 + (e & 7)] = f2bf_s(acc[r]);
      }
    }
  }
  __syncthreads();

  // c1d
  {
    int n = tid;
#pragma unroll
    for (int u = 0; u < 16; u++) {
      float acc = c1b[u];
#pragma unroll
      for (int c = 0; c < 8; c++)
        acc += c1w[u * 8 + c] * bf2f(ore[c * 264 + n]);
      xc1[u * 264 + n] = f2bf_s(acc);
    }
  }
  __syncthreads();

  // lin MFMA + residual
  {
    short8v a8[8];
#pragma unroll
    for (int kk = 0; kk < 8; kk++)
      a8[kk] = *(const short8v*)&xc1[row * 264 + kk * 32 + kg * 8];
    float* xo = xg + (size_t)b * 8192;
    for (int t = 0; t < 8; t++) {
      int nt = wid * 8 + t;
      const short* bb_base = linb + (nt * 16 + row) * 256 + kg * 8;
      f32x4 acc = {};
#pragma unroll
      for (int kk = 0; kk < 8; kk++) {
        short8v bb = *(const short8v*)(bb_base + kk * 32);
        acc = __builtin_amdgcn_mfma_f32_16x16x32_bf16(a8[kk], bb, acc, 0, 0, 0);
      }
      int m = nt * 16 + row;
      float lb = lin_b[m];
#pragma unroll
      for (int r = 0; r < 4; r++) {
        int u = kg * 4 + r;
        xo[u * 512 + m] += acc[r] + lb;
      }
    }
  }
}

// ---------------- K_FFN4: 1024 threads, staged weights, vector conv ----------
// LDS (149504 B):
//   [0, 77824)      sT [256 pos][152] bf16; during phase A:
//       +0          p_lds [256][40] bf16
//       +20480      f1w_lds [128][40] bf16
//   [77824, 149504) sY [128 c][280] bf16; later:
//       +0          pw_lds [128][152] bf16 (38912B) -> then f2out [32][257] f32
//       +38912      f2w_lds [32][152] bf16 (9728B)
__global__ __launch_bounds__(1024, 4) void k_ffn4(
    const float* __restrict__ x, const float* __restrict__ g,
    const float* __restrict__ beta, const short* __restrict__ f1wg,
    const float* __restrict__ f1b, const float* __restrict__ convW,
    const float* __restrict__ convB, const short* __restrict__ img,
    const float* __restrict__ pwbias, const float* __restrict__ f2b,
    float* __restrict__ xg) {
  __shared__ __align__(16) char smem[149504];
  short* p_lds = (short*)smem;                 // [256][40]
  short* f1w_lds = (short*)(smem + 20480);     // [128][40]
  short* sT = (short*)smem;                    // [256][152]
  short* sY = (short*)(smem + 77824);          // [128][280]
  short* pw_lds = (short*)(smem + 77824);      // [128][152]
  short* f2w_lds = (short*)(smem + 77824 + 38912);
  float* f2out = (float*)(smem + 77824);       // [32][257]

  int b = blockIdx.x, tid = threadIdx.x;
  int lane = tid & 63, wid = tid >> 6;         // wid 0..15
  int row = lane & 15, kg = lane >> 4;
  const float* xb = x + (size_t)b * 8192;
  float* xo = xg + (size_t)b * 8192;

  // ---- prefetch pw/f2 weight image into regs (3040 uint4) ----
  const uint4* imgu = (const uint4*)img;
  uint4 pf0 = imgu[tid], pf1 = imgu[tid + 1024];
  uint4 pf2 = {};
  if (tid < 992) pf2 = imgu[tid + 2048];

  // ---- stage f1w (640 uint4) ----
  if (tid < 640) ((uint4*)f1w_lds)[tid] = ((const uint4*)f1wg)[tid];

  // ---- LN2 + patches -> p_lds [pos][40] bf16 (one row per wave) ----
  {
    int r = wid;
    float vals[8];
    float s = 0.f, ss = 0.f;
#pragma unroll
    for (int j = 0; j < 8; j++) {
      float t = xb[r * 512 + lane + j * 64];
      vals[j] = t; s += t; ss += t * t;
    }
#pragma unroll
    for (int o = 32; o; o >>= 1) { s += __shfl_xor(s, o); ss += __shfl_xor(ss, o); }
    float m = s * (1.f / 512.f);
    float inv = rsqrtf(ss * (1.f / 512.f) - m * m + EPSF);
#pragma unroll
    for (int j = 0; j < 8; j++) {
      int col = lane + j * 64;
      float nv = (vals[j] - m) * inv * g[col] + beta[col];
      p_lds[(r * 16 + (col & 15)) * 40 + (col >> 4)] = f2bf_s(nv);
    }
  }
  __syncthreads();

  // ---- f1 MFMA: y1[o=128][pos=256], K=32; wave tile 32x64 ----
  {
    int o0 = (wid & 3) * 32, pos0 = (wid >> 2) * 64;
    short8v a0 = *(const short8v*)&f1w_lds[(o0 + row) * 40 + kg * 8];
    short8v a1 = *(const short8v*)&f1w_lds[(o0 + 16 + row) * 40 + kg * 8];
#pragma unroll
    for (int ni = 0; ni < 4; ni++) {
      short8v bb = *(const short8v*)&p_lds[(pos0 + ni * 16 + row) * 40 + kg * 8];
      f32x4 z = {};
      f32x4 c0 = __builtin_amdgcn_mfma_f32_16x16x32_bf16(a0, bb, z, 0, 0, 0);
      f32x4 c1 = __builtin_amdgcn_mfma_f32_16x16x32_bf16(a1, bb, z, 0, 0, 0);
      int pos = pos0 + ni * 16 + row;
#pragma unroll
      for (int r2 = 0; r2 < 4; r2++) {
        int c = o0 + kg * 4 + r2;
        sY[c * 280 + pos] = f2bf_s(fmaxf(c0[r2] + f1b[c], 0.f));
        sY[(c + 16) * 280 + pos] = f2bf_s(fmaxf(c1[r2] + f1b[c + 16], 0.f));
      }
    }
  }
  __syncthreads();

  // ---- depthwise 3x3 s1 (+folded BN) -> sT [pos][152] bf16 ----
  {
    int c = tid & 127, strip = tid >> 7;       // 2 rows per thread
    float w_[9];
#pragma unroll
    for (int k = 0; k < 9; k++) w_[k] = convW[k * 128 + c];
    float cb = convB[c];
#pragma unroll
    for (int j = 0; j < 2; j++) {
      int h = strip * 2 + j;
      float acc[16];
#pragma unroll
      for (int w = 0; w < 16; w++) acc[w] = cb;
#pragma unroll
      for (int rr = 0; rr < 3; rr++) {
        int rg = h - 1 + rr;
        if (rg < 0 || rg > 15) continue;
        short8v s0 = *(const short8v*)&sY[c * 280 + rg * 16];
        short8v s1 = *(const short8v*)&sY[c * 280 + rg * 16 + 8];
        float f[18];
        f[0] = 0.f; f[17] = 0.f;
#pragma unroll
        for (int i = 0; i < 8; i++) { f[1 + i] = bf2f(s0[i]); f[9 + i] = bf2f(s1[i]); }
        float w0 = w_[rr * 3], w1 = w_[rr * 3 + 1], w2 = w_[rr * 3 + 2];
#pragma unroll
        for (int w = 0; w < 16; w++)
          acc[w] += w0 * f[w] + w1 * f[w + 1] + w2 * f[w + 2];
      }
#pragma unroll
      for (int w = 0; w < 16; w++)
        sT[(h * 16 + w) * 152 + c] = f2bf_s(acc[w]);
    }
  }
  __syncthreads();

  // ---- drop prefetched weights into sY region (contiguous pw|f2w) ----
  {
    uint4* wdst = (uint4*)pw_lds;
    wdst[tid] = pf0; wdst[tid + 1024] = pf1;
    if (tid < 992) wdst[tid + 2048] = pf2;
  }
  __syncthreads();

  // ---- fpw MFMA: r[o=128][pos=256], K=128; wave tile 32x64 ----
  int o0 = (wid & 3) * 32, pos0 = (wid >> 2) * 64;
  f32x4 facc[2][4] = {};
#pragma unroll
  for (int kk = 0; kk < 4; kk++) {
    int k0 = kk * 32 + kg * 8;
    short8v a0 = *(const short8v*)&pw_lds[(o0 + row) * 152 + k0];
    short8v a1 = *(const short8v*)&pw_lds[(o0 + 16 + row) * 152 + k0];
    short8v bb[4];
#pragma unroll
    for (int ni = 0; ni < 4; ni++)
      bb[ni] = *(const short8v*)&sT[(pos0 + ni * 16 + row) * 152 + k0];
#pragma unroll
    for (int ni = 0; ni < 4; ni++) {
      facc[0][ni] = __builtin_amdgcn_mfma_f32_16x16x32_bf16(a0, bb[ni], facc[0][ni], 0, 0, 0);
      facc[1][ni] = __builtin_amdgcn_mfma_f32_16x16x32_bf16(a1, bb[ni], facc[1][ni], 0, 0, 0);
    }
  }
  __syncthreads();

  // ---- bias + ReLU -> sT[pos][o] (overwrite) ----
#pragma unroll
  for (int mi = 0; mi < 2; mi++) {
    int ob = o0 + mi * 16 + kg * 4;
    float pb0 = pwbias[ob], pb1 = pwbias[ob + 1];
    float pb2 = pwbias[ob + 2], pb3 = pwbias[ob + 3];
#pragma unroll
    for (int ni = 0; ni < 4; ni++) {
      int pos = pos0 + ni * 16 + row;
      short4v pk;
      pk.x = f2bf_s(fmaxf(facc[mi][ni][0] + pb0, 0.f));
      pk.y = f2bf_s(fmaxf(facc[mi][ni][1] + pb1, 0.f));
      pk.z = f2bf_s(fmaxf(facc[mi][ni][2] + pb2, 0.f));
      pk.w = f2bf_s(fmaxf(facc[mi][ni][3] + pb3, 0.f));
      *(short4v*)&sT[pos * 152 + ob] = pk;
    }
  }
  __syncthreads();

  // ---- f2 MFMA: out[d=32][pos=256], K=128; one 16-pos tile per wave ----
  {
    f32x4 acc2[2] = {};
    int pos = wid * 16 + row;
#pragma unroll
    for (int kk = 0; kk < 4; kk++) {
      int k0 = kk * 32 + kg * 8;
      short8v a0 = *(const short8v*)&f2w_lds[row * 152 + k0];
      short8v a1 = *(const short8v*)&f2w_lds[(16 + row) * 152 + k0];
      short8v bb = *(const short8v*)&sT[pos * 152 + k0];
      acc2[0] = __builtin_amdgcn_mfma_f32_16x16x32_bf16(a0, bb, acc2[0], 0, 0, 0);
      acc2[1] = __builtin_amdgcn_mfma_f32_16x16x32_bf16(a1, bb, acc2[1], 0, 0, 0);
    }
#pragma unroll
    for (int mi = 0; mi < 2; mi++)
#pragma unroll
      for (int r2 = 0; r2 < 4; r2++) {
        int d = mi * 16 + kg * 4 + r2;
        f2out[d * 257 + pos] = acc2[mi][r2];
      }
  }
  __syncthreads();

  // ---- residual epilogue (coalesced) ----
#pragma unroll
  for (int j = 0; j < 8; j++) {
    int idx = tid + j * 1024;            // p1*512 + d*16 + p2
    int dm = idx & 511;
    int d = dm >> 4, p2 = dm & 15;
    int p1 = idx >> 9;
    xo[idx] += f2out[d * 257 + p1 * 16 + p2] + f2b[d];
  }
}

extern "C" void kernel_launch(void* const* d_in, const int* in_sizes, int n_in,
                              void* d_out, int out_size, void* d_ws, size_t ws_size,
                              hipStream_t stream) {
  const float* x_in   = (const float*)d_in[0];
  const float* ln1_g  = (const float*)d_in[1];
  const float* ln1_b  = (const float*)d_in[2];
  const float* ln2_g  = (const float*)d_in[3];
  const float* ln2_b  = (const float*)d_in[4];
  const float* qkv_dw = (const float*)d_in[5];
  const float* qkv_bng = (const float*)d_in[6];
  const float* qkv_bnb = (const float*)d_in[7];
  const float* qkv_bnm = (const float*)d_in[8];
  const float* qkv_bnv = (const float*)d_in[9];
  const float* qkv_pw = (const float*)d_in[10];
  const float* position = (const float*)d_in[11];
  const float* c1d_w  = (const float*)d_in[12];
  const float* c1d_b  = (const float*)d_in[13];
  const float* lin_w  = (const float*)d_in[14];
  const float* lin_b  = (const float*)d_in[15];
  const float* f1_w   = (const float*)d_in[16];
  const float* f1_b   = (const float*)d_in[17];
  const float* fdw_w  = (const float*)d_in[18];
  const float* fdw_b  = (const float*)d_in[19];
  const float* f_bng  = (const float*)d_in[20];
  const float* f_bnb  = (const float*)d_in[21];
  const float* f_bnm  = (const float*)d_in[22];
  const float* f_bnv  = (const float*)d_in[23];
  const float* fpw_w  = (const float*)d_in[24];
  const float* fpw_b  = (const float*)d_in[25];
  const float* f2_w   = (const float*)d_in[26];
  const float* f2_b   = (const float*)d_in[27];

  float* xbuf = (float*)d_out;                 // running x lives in d_out
  short* qkvA = (short*)d_ws;                  // 7680
  short* linb = qkvA + 7680;                   // 262144
  short* f1wb = linb + 262144;                 // 10240
  short* img  = f1wb + 10240;                  // 48640
  float* convW = (float*)(img + 48640);        // 2304
  float* convB = convW + 2304;                 // 256

  hipMemcpyAsync(xbuf, x_in, (size_t)B_ * 8192 * sizeof(float),
                 hipMemcpyDeviceToDevice, stream);
  k_prep<<<1024, 256, 0, stream>>>(f1_w, fpw_w, f2_w, qkv_pw, lin_w,
      fdw_w, fdw_b, f_bng, f_bnb, f_bnm, f_bnv,
      qkvA, linb, f1wb, img, convW, convB);
  for (int l = 0; l < 2; l++) {
    k_att<<<B_, 256, 0, stream>>>(xbuf, ln1_g + l * 512, ln1_b + l * 512,
        qkv_dw + l * 864, qkv_bng + l * 96, qkv_bnb + l * 96,
        qkv_bnm + l * 96, qkv_bnv + l * 96, qkvA + l * 3840,
        position + l * 1024, c1d_w + l * 128, c1d_b + l * 16,
        linb + l * 131072, lin_b + l * 512, xbuf);
    k_ffn4<<<B_, 1024, 0, stream>>>(xbuf, ln2_g + l * 512, ln2_b + l * 512,
        f1wb + l * 5120, f1_b + l * 128, convW + l * 1152, convB + l * 128,
        img + l * 24320, fpw_b + l * 128, f2_b + l * 32, xbuf);
  }
}

// Round 9
// 400.137 us; speedup vs baseline: 1.9471x; 1.0577x over previous
//
#include <hip/hip_runtime.h>
#include <hip/hip_bf16.h>

#define B_ 2048
#define EPSF 1e-5f

typedef __attribute__((ext_vector_type(8))) short short8v;
typedef __attribute__((ext_vector_type(4))) short short4v;
typedef __attribute__((ext_vector_type(4))) float f32x4;

// float -> bf16 bits, round-to-nearest-even
__device__ __forceinline__ short f2bf_s(float f) {
  union { float f; unsigned u; } v; v.f = f;
  unsigned r = v.u + 0x7fffu + ((v.u >> 16) & 1u);
  return (short)(r >> 16);
}
__device__ __forceinline__ float bf2f(short s) {
  return __uint_as_float(((unsigned)(unsigned short)s) << 16);
}

// ---------------- weight prep -------------------------------------------------
__global__ __launch_bounds__(256) void k_prep(
    const float* __restrict__ f1_w, const float* __restrict__ fpw_w,
    const float* __restrict__ f2_w, const float* __restrict__ qkv_pw,
    const float* __restrict__ lin_w, const float* __restrict__ fdw_w,
    const float* __restrict__ fdw_b, const float* __restrict__ f_bng,
    const float* __restrict__ f_bnb, const float* __restrict__ f_bnm,
    const float* __restrict__ f_bnv, short* __restrict__ qkvA,
    short* __restrict__ linb, short* __restrict__ f1wb,
    short* __restrict__ img, float* __restrict__ convW,
    float* __restrict__ convB) {
  int i = blockIdx.x * 256 + threadIdx.x;
  if (i < 7680) {
    int l = i / 3840, r = i % 3840;
    int io = r / 40, c = r % 40;
    qkvA[i] = (c < 32) ? f2bf_s(qkv_pw[l * 3072 + io * 32 + c]) : (short)0;
  }
  if (i < 262144) linb[i] = f2bf_s(lin_w[i]);
  if (i < 10240) {
    int l = i / 5120, r = i % 5120, o = r / 40, kk = r % 40;
    f1wb[i] = (kk < 32) ? f2bf_s(f1_w[l * 4096 + o * 32 + kk]) : (short)0;
  }
  if (i < 48640) {
    int l = i / 24320, r = i % 24320;
    short val;
    if (r < 19456) {
      int o = r / 152, kk = r % 152;
      val = (kk < 128) ? f2bf_s(fpw_w[l * 16384 + o * 128 + kk]) : (short)0;
    } else {
      int r2 = r - 19456;
      int d = r2 / 152, kk = r2 % 152;
      val = (kk < 128) ? f2bf_s(f2_w[l * 4096 + d * 128 + kk]) : (short)0;
    }
    img[i] = val;
  }
  if (i < 256) {
    int l = i >> 7, c = i & 127;
    float scale = f_bng[l * 128 + c] * rsqrtf(f_bnv[l * 128 + c] + EPSF);
#pragma unroll
    for (int k = 0; k < 9; k++)
      convW[l * 1152 + k * 128 + c] = fdw_w[(l * 128 + c) * 9 + k] * scale;
    convB[l * 128 + c] =
        (fdw_b[l * 128 + c] - f_bnm[l * 128 + c]) * scale + f_bnb[l * 128 + c];
  }
}

// ---------------- K_ATT: fused LN1+qkv+attention+c1d+lin+residual ------------
// 512 threads (8 waves), LDS 62592 -> 2 blocks/CU.
__global__ __launch_bounds__(512) void k_att(
    const float* __restrict__ xin, const float* __restrict__ g,
    const float* __restrict__ beta, const float* __restrict__ dw,
    const float* __restrict__ bng, const float* __restrict__ bnb,
    const float* __restrict__ bnm, const float* __restrict__ bnv,
    const short* __restrict__ qkvA, const float* __restrict__ posn,
    const float* __restrict__ c1w, const float* __restrict__ c1b,
    const short* __restrict__ linb, const float* __restrict__ lin_b,
    float* __restrict__ xout) {
  __shared__ __align__(16) char smem[62592];
  float (*p)[257] = (float(*)[257])smem;
  float* sc  = (float*)(smem + 0);
  short* pa  = (short*)(smem + 4224);
  short* ore = (short*)(smem + 6784);
  short* xc1 = (short*)(smem + 11008);
  short* t3s = (short*)(smem + 32896);
  short* qe  = (short*)(smem + 48256);
  short* ke  = (short*)(smem + 52864);
  short* vt  = (short*)(smem + 57472);

  int b = blockIdx.x, tid = threadIdx.x;
  int lane = tid & 63, wid = tid >> 6;          // 8 waves
  int row = lane & 15, kg = lane >> 4;
  const float* xb = xin + (size_t)b * 8192;
  float* xo = xout + (size_t)b * 8192;

  // ---- early residual loads (T14): matches lin store pattern (4 tiles) ----
  float xr[4][4];
#pragma unroll
  for (int t = 0; t < 4; t++)
#pragma unroll
    for (int r = 0; r < 4; r++)
      xr[t][r] = xb[(kg * 4 + r) * 512 + (wid * 4 + t) * 16 + row];

  // ---- LN1 + to_patches (2 rows per wave) ----
  for (int r = wid; r < 16; r += 8) {
    float vals[8];
    float s = 0.f, ss = 0.f;
#pragma unroll
    for (int j = 0; j < 8; j++) {
      float t = xb[r * 512 + lane + j * 64];
      vals[j] = t; s += t; ss += t * t;
    }
#pragma unroll
    for (int o = 32; o; o >>= 1) { s += __shfl_xor(s, o); ss += __shfl_xor(ss, o); }
    float m = s * (1.f / 512.f);
    float inv = rsqrtf(ss * (1.f / 512.f) - m * m + EPSF);
#pragma unroll
    for (int j = 0; j < 8; j++) {
      int col = lane + j * 64;
      p[col >> 4][r * 16 + (col & 15)] = (vals[j] - m) * inv * g[col] + beta[col];
    }
  }
  __syncthreads();

  // ---- dw 3x3 s2 + BN (x3) -> t3[iw][pos][c]; thread = (c, oy, oxh) ----
  {
    int c = tid & 31, oy = (tid >> 5) & 7, oxh = tid >> 8;
    int base = oxh * 8 - 1;
    float ra[9], rb[9], rc[9];
    int iy0 = 2 * oy - 1;
#pragma unroll
    for (int k = 0; k < 9; k++) {
      int ic = base + k;
      bool cv = (ic >= 0);
      ra[k] = (cv && iy0 >= 0) ? p[c][iy0 * 16 + ic] : 0.f;
      rb[k] = cv ? p[c][(2 * oy) * 16 + ic] : 0.f;
      rc[k] = cv ? p[c][(2 * oy + 1) * 16 + ic] : 0.f;
    }
    for (int iw = 0; iw < 3; iw++) {
      const float* w9 = dw + iw * 288 + c * 9;
      float w00 = w9[0], w01 = w9[1], w02 = w9[2];
      float w10 = w9[3], w11 = w9[4], w12 = w9[5];
      float w20 = w9[6], w21 = w9[7], w22 = w9[8];
      float scale = bng[iw * 32 + c] * rsqrtf(bnv[iw * 32 + c] + EPSF);
      float shift = bnb[iw * 32 + c] - bnm[iw * 32 + c] * scale;
#pragma unroll
      for (int j = 0; j < 4; j++) {
        int ox = oxh * 4 + j;
        float acc = w00 * ra[2 * j] + w01 * ra[2 * j + 1] + w02 * ra[2 * j + 2]
                  + w10 * rb[2 * j] + w11 * rb[2 * j + 1] + w12 * rb[2 * j + 2]
                  + w20 * rc[2 * j] + w21 * rc[2 * j + 1] + w22 * rc[2 * j + 2];
        t3s[(iw * 64 + oy * 8 + ox) * 40 + c] = f2bf_s(acc * scale + shift);
      }
    }
  }
  __syncthreads();

  // ---- pw MFMA (one 16x16 tile per wave per iw) -> qe, ke, vt ----
  {
    int mi = wid & 1, ni = wid >> 1;              // ni 0..3
    for (int iw = 0; iw < 3; iw++) {
      short8v a = *(const short8v*)&qkvA[(iw * 32 + mi * 16 + row) * 40 + kg * 8];
      short8v bb = *(const short8v*)&t3s[(iw * 64 + ni * 16 + row) * 40 + kg * 8];
      f32x4 z = {};
      f32x4 acc = __builtin_amdgcn_mfma_f32_16x16x32_bf16(a, bb, z, 0, 0, 0);
      if (iw < 2) {
        short* tgt = (iw == 0) ? qe : ke;
#pragma unroll
        for (int r = 0; r < 4; r++) {
          int d = mi * 16 + kg * 4 + r;
          tgt[d * 72 + ni * 16 + row] = f2bf_s(acc[r]);
        }
      } else {
        int e = ni * 16 + row;
        int fb = mi * 16 + kg * 4;
        short4v v0;
        v0.x = f2bf_s(acc[0]); v0.y = f2bf_s(acc[1]);
        v0.z = f2bf_s(acc[2]); v0.w = f2bf_s(acc[3]);
        *(short4v*)&vt[e * 40 + fb] = v0;
      }
    }
  }
  __syncthreads();

  // ---- QK^T (waves 0-3) + position -> sc fp32 ----
  if (wid < 4) {
    int mi = wid & 1, ni = (wid >> 1) & 1;
    f32x4 acc = {};
#pragma unroll
    for (int kk = 0; kk < 2; kk++) {
      short8v a = *(const short8v*)&qe[(mi * 16 + row) * 72 + kk * 32 + kg * 8];
      short8v bb = *(const short8v*)&ke[(ni * 16 + row) * 72 + kk * 32 + kg * 8];
      acc = __builtin_amdgcn_mfma_f32_16x16x32_bf16(a, bb, acc, 0, 0, 0);
    }
#pragma unroll
    for (int r = 0; r < 4; r++) {
      int d = mi * 16 + kg * 4 + r, f = ni * 16 + row;
      sc[d * 33 + f] = acc[r] * 0.125f + posn[d * 32 + f];
    }
  }
  __syncthreads();

  // ---- softmax (first 256 threads) ----
  if (tid < 256) {
    int srow = tid >> 3, sg = tid & 7;
    float v0 = sc[srow * 33 + sg * 4 + 0];
    float v1 = sc[srow * 33 + sg * 4 + 1];
    float v2 = sc[srow * 33 + sg * 4 + 2];
    float v3 = sc[srow * 33 + sg * 4 + 3];
    float mx = fmaxf(fmaxf(v0, v1), fmaxf(v2, v3));
    mx = fmaxf(mx, __shfl_xor(mx, 1));
    mx = fmaxf(mx, __shfl_xor(mx, 2));
    mx = fmaxf(mx, __shfl_xor(mx, 4));
    float e0 = __expf(v0 - mx), e1 = __expf(v1 - mx);
    float e2 = __expf(v2 - mx), e3 = __expf(v3 - mx);
    float s = e0 + e1 + e2 + e3;
    s += __shfl_xor(s, 1); s += __shfl_xor(s, 2); s += __shfl_xor(s, 4);
    float inv = 1.f / s;
    short4v pk;
    pk.x = f2bf_s(e0 * inv); pk.y = f2bf_s(e1 * inv);
    pk.z = f2bf_s(e2 * inv); pk.w = f2bf_s(e3 * inv);
    *(short4v*)&pa[srow * 40 + sg * 4] = pk;
  }
  __syncthreads();

  // ---- PV (one tile per wave) -> ore[p1][d*8+p2] ----
  {
    int mi = wid & 1, et = wid >> 1;
    short8v a = *(const short8v*)&pa[(mi * 16 + row) * 40 + kg * 8];
    int e = et * 16 + row;
    short8v bb = *(const short8v*)&vt[e * 40 + kg * 8];
    f32x4 z = {};
    f32x4 acc = __builtin_amdgcn_mfma_f32_16x16x32_bf16(a, bb, z, 0, 0, 0);
#pragma unroll
    for (int r = 0; r < 4; r++) {
      int d = mi * 16 + kg * 4 + r;
      ore[(e >> 3) * 264 + d * 8 + (e & 7)] = f2bf_s(acc[r]);
    }
  }
  __syncthreads();

  // ---- c1d: thread = (n, uh), 8 u each ----
  {
    int n = tid & 255, uh = tid >> 8;
    float o8[8];
#pragma unroll
    for (int c = 0; c < 8; c++) o8[c] = bf2f(ore[c * 264 + n]);
#pragma unroll
    for (int uu = 0; uu < 8; uu++) {
      int u = uh * 8 + uu;
      float acc = c1b[u];
#pragma unroll
      for (int c = 0; c < 8; c++) acc += c1w[u * 8 + c] * o8[c];
      xc1[u * 264 + n] = f2bf_s(acc);
    }
  }
  __syncthreads();

  // ---- lin MFMA (4 tiles per wave -> m covers 0..511) + bias + residual ----
  {
    short8v a8[8];
#pragma unroll
    for (int kk = 0; kk < 8; kk++)
      a8[kk] = *(const short8v*)&xc1[row * 264 + kk * 32 + kg * 8];
#pragma unroll
    for (int t = 0; t < 4; t++) {
      int nt = wid * 4 + t;
      const short* bb_base = linb + (nt * 16 + row) * 256 + kg * 8;
      f32x4 acc = {};
#pragma unroll
      for (int kk = 0; kk < 8; kk++) {
        short8v bb = *(const short8v*)(bb_base + kk * 32);
        acc = __builtin_amdgcn_mfma_f32_16x16x32_bf16(a8[kk], bb, acc, 0, 0, 0);
      }
      int m = nt * 16 + row;
      float lb = lin_b[m];
#pragma unroll
      for (int r = 0; r < 4; r++) {
        int u = kg * 4 + r;
        xo[u * 512 + m] = xr[t][r] + acc[r] + lb;
      }
    }
  }
}

// ---------------- K_FFN4: 1024 threads, staged weights, vector conv ----------
__global__ __launch_bounds__(1024, 4) void k_ffn4(
    const float* __restrict__ x, const float* __restrict__ g,
    const float* __restrict__ beta, const short* __restrict__ f1wg,
    const float* __restrict__ f1b, const float* __restrict__ convW,
    const float* __restrict__ convB, const short* __restrict__ img,
    const float* __restrict__ pwbias, const float* __restrict__ f2b,
    float* __restrict__ xg) {
  __shared__ __align__(16) char smem[149504];
  short* p_lds = (short*)smem;                 // [256][40]
  short* f1w_lds = (short*)(smem + 20480);     // [128][40]
  short* sT = (short*)smem;                    // [256][152]
  short* sY = (short*)(smem + 77824);          // [128][280]
  short* pw_lds = (short*)(smem + 77824);      // [128][152]
  short* f2w_lds = (short*)(smem + 77824 + 38912);

  int b = blockIdx.x, tid = threadIdx.x;
  int lane = tid & 63, wid = tid >> 6;         // wid 0..15
  int row = lane & 15, kg = lane >> 4;
  const float* xb = x + (size_t)b * 8192;
  float* xo = xg + (size_t)b * 8192;

  // ---- prefetch pw/f2 weight image into regs ----
  const uint4* imgu = (const uint4*)img;
  uint4 pf0 = imgu[tid], pf1 = imgu[tid + 1024];
  uint4 pf2 = {};
  if (tid < 992) pf2 = imgu[tid + 2048];

  // ---- early residual loads (T14): matches f2 store pattern ----
  float xr[2][4];
#pragma unroll
  for (int mi = 0; mi < 2; mi++)
#pragma unroll
    for (int r2 = 0; r2 < 4; r2++)
      xr[mi][r2] = xo[wid * 512 + mi * 256 + kg * 64 + r2 * 16 + row];

  // ---- stage f1w ----
  if (tid < 640) ((uint4*)f1w_lds)[tid] = ((const uint4*)f1wg)[tid];

  // ---- LN2 + patches -> p_lds [pos][40] bf16 (one row per wave) ----
  {
    int r = wid;
    float vals[8];
    float s = 0.f, ss = 0.f;
#pragma unroll
    for (int j = 0; j < 8; j++) {
      float t = xb[r * 512 + lane + j * 64];
      vals[j] = t; s += t; ss += t * t;
    }
#pragma unroll
    for (int o = 32; o; o >>= 1) { s += __shfl_xor(s, o); ss += __shfl_xor(ss, o); }
    float m = s * (1.f / 512.f);
    float inv = rsqrtf(ss * (1.f / 512.f) - m * m + EPSF);
#pragma unroll
    for (int j = 0; j < 8; j++) {
      int col = lane + j * 64;
      float nv = (vals[j] - m) * inv * g[col] + beta[col];
      p_lds[(r * 16 + (col & 15)) * 40 + (col >> 4)] = f2bf_s(nv);
    }
  }
  __syncthreads();

  // ---- f1 MFMA: y1[o=128][pos=256], K=32; wave tile 32x64 ----
  {
    int o0 = (wid & 3) * 32, pos0 = (wid >> 2) * 64;
    short8v a0 = *(const short8v*)&f1w_lds[(o0 + row) * 40 + kg * 8];
    short8v a1 = *(const short8v*)&f1w_lds[(o0 + 16 + row) * 40 + kg * 8];
#pragma unroll
    for (int ni = 0; ni < 4; ni++) {
      short8v bb = *(const short8v*)&p_lds[(pos0 + ni * 16 + row) * 40 + kg * 8];
      f32x4 z = {};
      f32x4 c0 = __builtin_amdgcn_mfma_f32_16x16x32_bf16(a0, bb, z, 0, 0, 0);
      f32x4 c1 = __builtin_amdgcn_mfma_f32_16x16x32_bf16(a1, bb, z, 0, 0, 0);
      int pos = pos0 + ni * 16 + row;
#pragma unroll
      for (int r2 = 0; r2 < 4; r2++) {
        int c = o0 + kg * 4 + r2;
        sY[c * 280 + pos] = f2bf_s(fmaxf(c0[r2] + f1b[c], 0.f));
        sY[(c + 16) * 280 + pos] = f2bf_s(fmaxf(c1[r2] + f1b[c + 16], 0.f));
      }
    }
  }
  __syncthreads();

  // ---- depthwise 3x3 s1 (+folded BN) -> sT [pos][152] bf16 ----
  {
    int c = tid & 127, strip = tid >> 7;       // 2 rows per thread
    float w_[9];
#pragma unroll
    for (int k = 0; k < 9; k++) w_[k] = convW[k * 128 + c];
    float cb = convB[c];
#pragma unroll
    for (int j = 0; j < 2; j++) {
      int h = strip * 2 + j;
      float acc[16];
#pragma unroll
      for (int w = 0; w < 16; w++) acc[w] = cb;
#pragma unroll
      for (int rr = 0; rr < 3; rr++) {
        int rg = h - 1 + rr;
        if (rg < 0 || rg > 15) continue;
        short8v s0 = *(const short8v*)&sY[c * 280 + rg * 16];
        short8v s1 = *(const short8v*)&sY[c * 280 + rg * 16 + 8];
        float f[18];
        f[0] = 0.f; f[17] = 0.f;
#pragma unroll
        for (int i = 0; i < 8; i++) { f[1 + i] = bf2f(s0[i]); f[9 + i] = bf2f(s1[i]); }
        float w0 = w_[rr * 3], w1 = w_[rr * 3 + 1], w2 = w_[rr * 3 + 2];
#pragma unroll
        for (int w = 0; w < 16; w++)
          acc[w] += w0 * f[w] + w1 * f[w + 1] + w2 * f[w + 2];
      }
#pragma unroll
      for (int w = 0; w < 16; w++)
        sT[(h * 16 + w) * 152 + c] = f2bf_s(acc[w]);
    }
  }
  __syncthreads();

  // ---- drop prefetched weights into sY region ----
  {
    uint4* wdst = (uint4*)pw_lds;
    wdst[tid] = pf0; wdst[tid + 1024] = pf1;
    if (tid < 992) wdst[tid + 2048] = pf2;
  }
  __syncthreads();

  // ---- fpw MFMA: r[o=128][pos=256], K=128; wave tile 32x64 ----
  int o0 = (wid & 3) * 32, pos0 = (wid >> 2) * 64;
  f32x4 facc[2][4] = {};
#pragma unroll
  for (int kk = 0; kk < 4; kk++) {
    int k0 = kk * 32 + kg * 8;
    short8v a0 = *(const short8v*)&pw_lds[(o0 + row) * 152 + k0];
    short8v a1 = *(const short8v*)&pw_lds[(o0 + 16 + row) * 152 + k0];
    short8v bb[4];
#pragma unroll
    for (int ni = 0; ni < 4; ni++)
      bb[ni] = *(const short8v*)&sT[(pos0 + ni * 16 + row) * 152 + k0];
#pragma unroll
    for (int ni = 0; ni < 4; ni++) {
      facc[0][ni] = __builtin_amdgcn_mfma_f32_16x16x32_bf16(a0, bb[ni], facc[0][ni], 0, 0, 0);
      facc[1][ni] = __builtin_amdgcn_mfma_f32_16x16x32_bf16(a1, bb[ni], facc[1][ni], 0, 0, 0);
    }
  }
  __syncthreads();

  // ---- bias + ReLU -> sT[pos][o] (overwrite) ----
#pragma unroll
  for (int mi = 0; mi < 2; mi++) {
    int ob = o0 + mi * 16 + kg * 4;
    float pb0 = pwbias[ob], pb1 = pwbias[ob + 1];
    float pb2 = pwbias[ob + 2], pb3 = pwbias[ob + 3];
#pragma unroll
    for (int ni = 0; ni < 4; ni++) {
      int pos = pos0 + ni * 16 + row;
      short4v pk;
      pk.x = f2bf_s(fmaxf(facc[mi][ni][0] + pb0, 0.f));
      pk.y = f2bf_s(fmaxf(facc[mi][ni][1] + pb1, 0.f));
      pk.z = f2bf_s(fmaxf(facc[mi][ni][2] + pb2, 0.f));
      pk.w = f2bf_s(fmaxf(facc[mi][ni][3] + pb3, 0.f));
      *(short4v*)&sT[pos * 152 + ob] = pk;
    }
  }
  __syncthreads();

  // ---- f2 MFMA: out[d=32][pos=256], K=128; direct residual store ----
  {
    f32x4 acc2[2] = {};
    int pos = wid * 16 + row;
#pragma unroll
    for (int kk = 0; kk < 4; kk++) {
      int k0 = kk * 32 + kg * 8;
      short8v a0 = *(const short8v*)&f2w_lds[row * 152 + k0];
      short8v a1 = *(const short8v*)&f2w_lds[(16 + row) * 152 + k0];
      short8v bb = *(const short8v*)&sT[pos * 152 + k0];
      acc2[0] = __builtin_amdgcn_mfma_f32_16x16x32_bf16(a0, bb, acc2[0], 0, 0, 0);
      acc2[1] = __builtin_amdgcn_mfma_f32_16x16x32_bf16(a1, bb, acc2[1], 0, 0, 0);
    }
#pragma unroll
    for (int mi = 0; mi < 2; mi++)
#pragma unroll
      for (int r2 = 0; r2 < 4; r2++) {
        int d = mi * 16 + kg * 4 + r2;
        xo[wid * 512 + mi * 256 + kg * 64 + r2 * 16 + row] =
            xr[mi][r2] + acc2[mi][r2] + f2b[d];
      }
  }
}

extern "C" void kernel_launch(void* const* d_in, const int* in_sizes, int n_in,
                              void* d_out, int out_size, void* d_ws, size_t ws_size,
                              hipStream_t stream) {
  const float* x_in   = (const float*)d_in[0];
  const float* ln1_g  = (const float*)d_in[1];
  const float* ln1_b  = (const float*)d_in[2];
  const float* ln2_g  = (const float*)d_in[3];
  const float* ln2_b  = (const float*)d_in[4];
  const float* qkv_dw = (const float*)d_in[5];
  const float* qkv_bng = (const float*)d_in[6];
  const float* qkv_bnb = (const float*)d_in[7];
  const float* qkv_bnm = (const float*)d_in[8];
  const float* qkv_bnv = (const float*)d_in[9];
  const float* qkv_pw = (const float*)d_in[10];
  const float* position = (const float*)d_in[11];
  const float* c1d_w  = (const float*)d_in[12];
  const float* c1d_b  = (const float*)d_in[13];
  const float* lin_w  = (const float*)d_in[14];
  const float* lin_b  = (const float*)d_in[15];
  const float* f1_w   = (const float*)d_in[16];
  const float* f1_b   = (const float*)d_in[17];
  const float* fdw_w  = (const float*)d_in[18];
  const float* fdw_b  = (const float*)d_in[19];
  const float* f_bng  = (const float*)d_in[20];
  const float* f_bnb  = (const float*)d_in[21];
  const float* f_bnm  = (const float*)d_in[22];
  const float* f_bnv  = (const float*)d_in[23];
  const float* fpw_w  = (const float*)d_in[24];
  const float* fpw_b  = (const float*)d_in[25];
  const float* f2_w   = (const float*)d_in[26];
  const float* f2_b   = (const float*)d_in[27];

  float* xbuf = (float*)d_out;                 // running x lives in d_out
  short* qkvA = (short*)d_ws;                  // 7680
  short* linb = qkvA + 7680;                   // 262144
  short* f1wb = linb + 262144;                 // 10240
  short* img  = f1wb + 10240;                  // 48640
  float* convW = (float*)(img + 48640);        // 2304
  float* convB = convW + 2304;                 // 256

  k_prep<<<1024, 256, 0, stream>>>(f1_w, fpw_w, f2_w, qkv_pw, lin_w,
      fdw_w, fdw_b, f_bng, f_bnb, f_bnm, f_bnv,
      qkvA, linb, f1wb, img, convW, convB);
  for (int l = 0; l < 2; l++) {
    const float* xin = (l == 0) ? x_in : xbuf;
    k_att<<<B_, 512, 0, stream>>>(xin, ln1_g + l * 512, ln1_b + l * 512,
        qkv_dw + l * 864, qkv_bng + l * 96, qkv_bnb + l * 96,
        qkv_bnm + l * 96, qkv_bnv + l * 96, qkvA + l * 3840,
        position + l * 1024, c1d_w + l * 128, c1d_b + l * 16,
        linb + l * 131072, lin_b + l * 512, xbuf);
    k_ffn4<<<B_, 1024, 0, stream>>>(xbuf, ln2_g + l * 512, ln2_b + l * 512,
        f1wb + l * 5120, f1_b + l * 128, convW + l * 1152, convB + l * 128,
        img + l * 24320, fpw_b + l * 128, f2_b + l * 32, xbuf);
  }
}

// Round 10
// 383.785 us; speedup vs baseline: 2.0300x; 1.0426x over previous
//
#include <hip/hip_runtime.h>
#include <hip/hip_bf16.h>

#define B_ 2048
#define EPSF 1e-5f

typedef __attribute__((ext_vector_type(8))) short short8v;
typedef __attribute__((ext_vector_type(4))) short short4v;
typedef __attribute__((ext_vector_type(4))) float f32x4;

// float -> bf16 bits via compiler-native conversion (v_cvt_pk_bf16_f32 on gfx950)
__device__ __forceinline__ short f2bf_s(float f) {
  __hip_bfloat16 h = __float2bfloat16(f);
  return *reinterpret_cast<const short*>(&h);
}
__device__ __forceinline__ float bf2f(short s) {
  return __uint_as_float(((unsigned)(unsigned short)s) << 16);
}

// ---------------- weight prep -------------------------------------------------
__global__ __launch_bounds__(256) void k_prep(
    const float* __restrict__ f1_w, const float* __restrict__ fpw_w,
    const float* __restrict__ f2_w, const float* __restrict__ qkv_pw,
    const float* __restrict__ lin_w, const float* __restrict__ fdw_w,
    const float* __restrict__ fdw_b, const float* __restrict__ f_bng,
    const float* __restrict__ f_bnb, const float* __restrict__ f_bnm,
    const float* __restrict__ f_bnv, short* __restrict__ qkvA,
    short* __restrict__ linb, short* __restrict__ f1wb,
    short* __restrict__ img, float* __restrict__ convW,
    float* __restrict__ convB) {
  int i = blockIdx.x * 256 + threadIdx.x;
  if (i < 7680) {
    int l = i / 3840, r = i % 3840;
    int io = r / 40, c = r % 40;
    qkvA[i] = (c < 32) ? f2bf_s(qkv_pw[l * 3072 + io * 32 + c]) : (short)0;
  }
  if (i < 262144) linb[i] = f2bf_s(lin_w[i]);
  if (i < 10240) {
    int l = i / 5120, r = i % 5120, o = r / 40, kk = r % 40;
    f1wb[i] = (kk < 32) ? f2bf_s(f1_w[l * 4096 + o * 32 + kk]) : (short)0;
  }
  if (i < 48640) {
    int l = i / 24320, r = i % 24320;
    short val;
    if (r < 19456) {
      int o = r / 152, kk = r % 152;
      val = (kk < 128) ? f2bf_s(fpw_w[l * 16384 + o * 128 + kk]) : (short)0;
    } else {
      int r2 = r - 19456;
      int d = r2 / 152, kk = r2 % 152;
      val = (kk < 128) ? f2bf_s(f2_w[l * 4096 + d * 128 + kk]) : (short)0;
    }
    img[i] = val;
  }
  if (i < 256) {
    int l = i >> 7, c = i & 127;
    float scale = f_bng[l * 128 + c] * rsqrtf(f_bnv[l * 128 + c] + EPSF);
#pragma unroll
    for (int k = 0; k < 9; k++)
      convW[l * 1152 + k * 128 + c] = fdw_w[(l * 128 + c) * 9 + k] * scale;
    convB[l * 128 + c] =
        (fdw_b[l * 128 + c] - f_bnm[l * 128 + c]) * scale + f_bnb[l * 128 + c];
  }
}

// ---------------- K_ATT: fused LN1+qkv+attention+c1d+lin+residual ------------
// 512 threads (8 waves), LDS 62592 -> 2 blocks/CU.
__global__ __launch_bounds__(512) void k_att(
    const float* __restrict__ xin, const float* __restrict__ g,
    const float* __restrict__ beta, const float* __restrict__ dw,
    const float* __restrict__ bng, const float* __restrict__ bnb,
    const float* __restrict__ bnm, const float* __restrict__ bnv,
    const short* __restrict__ qkvA, const float* __restrict__ posn,
    const float* __restrict__ c1w, const float* __restrict__ c1b,
    const short* __restrict__ linb, const float* __restrict__ lin_b,
    float* __restrict__ xout) {
  __shared__ __align__(16) char smem[62592];
  float (*p)[257] = (float(*)[257])smem;
  float* sc  = (float*)(smem + 0);
  short* pa  = (short*)(smem + 4224);
  short* ore = (short*)(smem + 6784);
  short* xc1 = (short*)(smem + 11008);
  short* t3s = (short*)(smem + 32896);
  short* qe  = (short*)(smem + 48256);
  short* ke  = (short*)(smem + 52864);
  short* vt  = (short*)(smem + 57472);

  int b = blockIdx.x, tid = threadIdx.x;
  int lane = tid & 63, wid = tid >> 6;          // 8 waves
  int row = lane & 15, kg = lane >> 4;
  const float* xb = xin + (size_t)b * 8192;
  float* xo = xout + (size_t)b * 8192;

  // ---- early residual loads (T14): matches lin store pattern (4 tiles) ----
  float xr[4][4];
#pragma unroll
  for (int t = 0; t < 4; t++)
#pragma unroll
    for (int r = 0; r < 4; r++)
      xr[t][r] = xb[(kg * 4 + r) * 512 + (wid * 4 + t) * 16 + row];

  // ---- LN1 + to_patches (2 rows per wave) ----
  for (int r = wid; r < 16; r += 8) {
    float vals[8];
    float s = 0.f, ss = 0.f;
#pragma unroll
    for (int j = 0; j < 8; j++) {
      float t = xb[r * 512 + lane + j * 64];
      vals[j] = t; s += t; ss += t * t;
    }
#pragma unroll
    for (int o = 32; o; o >>= 1) { s += __shfl_xor(s, o); ss += __shfl_xor(ss, o); }
    float m = s * (1.f / 512.f);
    float inv = rsqrtf(ss * (1.f / 512.f) - m * m + EPSF);
#pragma unroll
    for (int j = 0; j < 8; j++) {
      int col = lane + j * 64;
      p[col >> 4][r * 16 + (col & 15)] = (vals[j] - m) * inv * g[col] + beta[col];
    }
  }
  __syncthreads();

  // ---- dw 3x3 s2 + BN (x3) -> t3[iw][pos][c]; thread = (c, oy, oxh) ----
  {
    int c = tid & 31, oy = (tid >> 5) & 7, oxh = tid >> 8;
    int base = oxh * 8 - 1;
    float ra[9], rb[9], rc[9];
    int iy0 = 2 * oy - 1;
#pragma unroll
    for (int k = 0; k < 9; k++) {
      int ic = base + k;
      bool cv = (ic >= 0);
      ra[k] = (cv && iy0 >= 0) ? p[c][iy0 * 16 + ic] : 0.f;
      rb[k] = cv ? p[c][(2 * oy) * 16 + ic] : 0.f;
      rc[k] = cv ? p[c][(2 * oy + 1) * 16 + ic] : 0.f;
    }
    for (int iw = 0; iw < 3; iw++) {
      const float* w9 = dw + iw * 288 + c * 9;
      float w00 = w9[0], w01 = w9[1], w02 = w9[2];
      float w10 = w9[3], w11 = w9[4], w12 = w9[5];
      float w20 = w9[6], w21 = w9[7], w22 = w9[8];
      float scale = bng[iw * 32 + c] * rsqrtf(bnv[iw * 32 + c] + EPSF);
      float shift = bnb[iw * 32 + c] - bnm[iw * 32 + c] * scale;
#pragma unroll
      for (int j = 0; j < 4; j++) {
        int ox = oxh * 4 + j;
        float acc = w00 * ra[2 * j] + w01 * ra[2 * j + 1] + w02 * ra[2 * j + 2]
                  + w10 * rb[2 * j] + w11 * rb[2 * j + 1] + w12 * rb[2 * j + 2]
                  + w20 * rc[2 * j] + w21 * rc[2 * j + 1] + w22 * rc[2 * j + 2];
        t3s[(iw * 64 + oy * 8 + ox) * 40 + c] = f2bf_s(acc * scale + shift);
      }
    }
  }
  __syncthreads();

  // ---- pw MFMA (one 16x16 tile per wave per iw) -> qe, ke, vt ----
  {
    int mi = wid & 1, ni = wid >> 1;              // ni 0..3
    for (int iw = 0; iw < 3; iw++) {
      short8v a = *(const short8v*)&qkvA[(iw * 32 + mi * 16 + row) * 40 + kg * 8];
      short8v bb = *(const short8v*)&t3s[(iw * 64 + ni * 16 + row) * 40 + kg * 8];
      f32x4 z = {};
      f32x4 acc = __builtin_amdgcn_mfma_f32_16x16x32_bf16(a, bb, z, 0, 0, 0);
      if (iw < 2) {
        short* tgt = (iw == 0) ? qe : ke;
#pragma unroll
        for (int r = 0; r < 4; r++) {
          int d = mi * 16 + kg * 4 + r;
          tgt[d * 72 + ni * 16 + row] = f2bf_s(acc[r]);
        }
      } else {
        int e = ni * 16 + row;
        int fb = mi * 16 + kg * 4;
        short4v v0;
        v0.x = f2bf_s(acc[0]); v0.y = f2bf_s(acc[1]);
        v0.z = f2bf_s(acc[2]); v0.w = f2bf_s(acc[3]);
        *(short4v*)&vt[e * 40 + fb] = v0;
      }
    }
  }
  __syncthreads();

  // ---- QK^T (waves 0-3) + position -> sc fp32 ----
  if (wid < 4) {
    int mi = wid & 1, ni = (wid >> 1) & 1;
    f32x4 acc = {};
#pragma unroll
    for (int kk = 0; kk < 2; kk++) {
      short8v a = *(const short8v*)&qe[(mi * 16 + row) * 72 + kk * 32 + kg * 8];
      short8v bb = *(const short8v*)&ke[(ni * 16 + row) * 72 + kk * 32 + kg * 8];
      acc = __builtin_amdgcn_mfma_f32_16x16x32_bf16(a, bb, acc, 0, 0, 0);
    }
#pragma unroll
    for (int r = 0; r < 4; r++) {
      int d = mi * 16 + kg * 4 + r, f = ni * 16 + row;
      sc[d * 33 + f] = acc[r] * 0.125f + posn[d * 32 + f];
    }
  }
  __syncthreads();

  // ---- softmax (first 256 threads) ----
  if (tid < 256) {
    int srow = tid >> 3, sg = tid & 7;
    float v0 = sc[srow * 33 + sg * 4 + 0];
    float v1 = sc[srow * 33 + sg * 4 + 1];
    float v2 = sc[srow * 33 + sg * 4 + 2];
    float v3 = sc[srow * 33 + sg * 4 + 3];
    float mx = fmaxf(fmaxf(v0, v1), fmaxf(v2, v3));
    mx = fmaxf(mx, __shfl_xor(mx, 1));
    mx = fmaxf(mx, __shfl_xor(mx, 2));
    mx = fmaxf(mx, __shfl_xor(mx, 4));
    float e0 = __expf(v0 - mx), e1 = __expf(v1 - mx);
    float e2 = __expf(v2 - mx), e3 = __expf(v3 - mx);
    float s = e0 + e1 + e2 + e3;
    s += __shfl_xor(s, 1); s += __shfl_xor(s, 2); s += __shfl_xor(s, 4);
    float inv = 1.f / s;
    short4v pk;
    pk.x = f2bf_s(e0 * inv); pk.y = f2bf_s(e1 * inv);
    pk.z = f2bf_s(e2 * inv); pk.w = f2bf_s(e3 * inv);
    *(short4v*)&pa[srow * 40 + sg * 4] = pk;
  }
  __syncthreads();

  // ---- PV (one tile per wave) -> ore[p1][d*8+p2] ----
  {
    int mi = wid & 1, et = wid >> 1;
    short8v a = *(const short8v*)&pa[(mi * 16 + row) * 40 + kg * 8];
    int e = et * 16 + row;
    short8v bb = *(const short8v*)&vt[e * 40 + kg * 8];
    f32x4 z = {};
    f32x4 acc = __builtin_amdgcn_mfma_f32_16x16x32_bf16(a, bb, z, 0, 0, 0);
#pragma unroll
    for (int r = 0; r < 4; r++) {
      int d = mi * 16 + kg * 4 + r;
      ore[(e >> 3) * 264 + d * 8 + (e & 7)] = f2bf_s(acc[r]);
    }
  }
  __syncthreads();

  // ---- c1d: thread = (n, uh), 8 u each ----
  {
    int n = tid & 255, uh = tid >> 8;
    float o8[8];
#pragma unroll
    for (int c = 0; c < 8; c++) o8[c] = bf2f(ore[c * 264 + n]);
#pragma unroll
    for (int uu = 0; uu < 8; uu++) {
      int u = uh * 8 + uu;
      float acc = c1b[u];
#pragma unroll
      for (int c = 0; c < 8; c++) acc += c1w[u * 8 + c] * o8[c];
      xc1[u * 264 + n] = f2bf_s(acc);
    }
  }
  __syncthreads();

  // ---- lin MFMA (4 tiles per wave -> m covers 0..511) + bias + residual ----
  {
    short8v a8[8];
#pragma unroll
    for (int kk = 0; kk < 8; kk++)
      a8[kk] = *(const short8v*)&xc1[row * 264 + kk * 32 + kg * 8];
#pragma unroll
    for (int t = 0; t < 4; t++) {
      int nt = wid * 4 + t;
      const short* bb_base = linb + (nt * 16 + row) * 256 + kg * 8;
      f32x4 acc = {};
#pragma unroll
      for (int kk = 0; kk < 8; kk++) {
        short8v bb = *(const short8v*)(bb_base + kk * 32);
        acc = __builtin_amdgcn_mfma_f32_16x16x32_bf16(a8[kk], bb, acc, 0, 0, 0);
      }
      int m = nt * 16 + row;
      float lb = lin_b[m];
#pragma unroll
      for (int r = 0; r < 4; r++) {
        int u = kg * 4 + r;
        xo[u * 512 + m] = xr[t][r] + acc[r] + lb;
      }
    }
  }
}

// ---------------- K_FFN4: 1024 threads, staged weights, vector conv ----------
__global__ __launch_bounds__(1024, 4) void k_ffn4(
    const float* __restrict__ x, const float* __restrict__ g,
    const float* __restrict__ beta, const short* __restrict__ f1wg,
    const float* __restrict__ f1b, const float* __restrict__ convW,
    const float* __restrict__ convB, const short* __restrict__ img,
    const float* __restrict__ pwbias, const float* __restrict__ f2b,
    float* __restrict__ xg) {
  __shared__ __align__(16) char smem[149504];
  short* p_lds = (short*)smem;                 // [256][40]
  short* f1w_lds = (short*)(smem + 20480);     // [128][40]
  short* sT = (short*)smem;                    // [256][152]
  short* sY = (short*)(smem + 77824);          // [128][280]
  short* pw_lds = (short*)(smem + 77824);      // [128][152]
  short* f2w_lds = (short*)(smem + 77824 + 38912);

  int b = blockIdx.x, tid = threadIdx.x;
  int lane = tid & 63, wid = tid >> 6;         // wid 0..15
  int row = lane & 15, kg = lane >> 4;
  const float* xb = x + (size_t)b * 8192;
  float* xo = xg + (size_t)b * 8192;

  // ---- prefetch pw/f2 weight image into regs ----
  const uint4* imgu = (const uint4*)img;
  uint4 pf0 = imgu[tid], pf1 = imgu[tid + 1024];
  uint4 pf2 = {};
  if (tid < 992) pf2 = imgu[tid + 2048];

  // ---- prefetch conv weights (hide L2 latency under LN/f1 phases) ----
  int cch = tid & 127;
  float w_[9];
#pragma unroll
  for (int k = 0; k < 9; k++) w_[k] = convW[k * 128 + cch];
  float cb = convB[cch];

  // ---- early residual loads (T14): matches f2 store pattern ----
  float xr[2][4];
#pragma unroll
  for (int mi = 0; mi < 2; mi++)
#pragma unroll
    for (int r2 = 0; r2 < 4; r2++)
      xr[mi][r2] = xo[wid * 512 + mi * 256 + kg * 64 + r2 * 16 + row];

  // ---- stage f1w ----
  if (tid < 640) ((uint4*)f1w_lds)[tid] = ((const uint4*)f1wg)[tid];

  // ---- LN2 + patches -> p_lds [pos][40] bf16 (one row per wave) ----
  {
    int r = wid;
    float vals[8];
    float s = 0.f, ss = 0.f;
#pragma unroll
    for (int j = 0; j < 8; j++) {
      float t = xb[r * 512 + lane + j * 64];
      vals[j] = t; s += t; ss += t * t;
    }
#pragma unroll
    for (int o = 32; o; o >>= 1) { s += __shfl_xor(s, o); ss += __shfl_xor(ss, o); }
    float m = s * (1.f / 512.f);
    float inv = rsqrtf(ss * (1.f / 512.f) - m * m + EPSF);
#pragma unroll
    for (int j = 0; j < 8; j++) {
      int col = lane + j * 64;
      float nv = (vals[j] - m) * inv * g[col] + beta[col];
      p_lds[(r * 16 + (col & 15)) * 40 + (col >> 4)] = f2bf_s(nv);
    }
  }
  __syncthreads();

  // ---- f1 MFMA: y1[o=128][pos=256], K=32; wave tile 32x64 ----
  {
    int o0 = (wid & 3) * 32, pos0 = (wid >> 2) * 64;
    short8v a0 = *(const short8v*)&f1w_lds[(o0 + row) * 40 + kg * 8];
    short8v a1 = *(const short8v*)&f1w_lds[(o0 + 16 + row) * 40 + kg * 8];
#pragma unroll
    for (int ni = 0; ni < 4; ni++) {
      short8v bb = *(const short8v*)&p_lds[(pos0 + ni * 16 + row) * 40 + kg * 8];
      f32x4 z = {};
      f32x4 c0 = __builtin_amdgcn_mfma_f32_16x16x32_bf16(a0, bb, z, 0, 0, 0);
      f32x4 c1 = __builtin_amdgcn_mfma_f32_16x16x32_bf16(a1, bb, z, 0, 0, 0);
      int pos = pos0 + ni * 16 + row;
#pragma unroll
      for (int r2 = 0; r2 < 4; r2++) {
        int c = o0 + kg * 4 + r2;
        sY[c * 280 + pos] = f2bf_s(fmaxf(c0[r2] + f1b[c], 0.f));
        sY[(c + 16) * 280 + pos] = f2bf_s(fmaxf(c1[r2] + f1b[c + 16], 0.f));
      }
    }
  }
  __syncthreads();

  // ---- depthwise 3x3 s1 (+folded BN) -> sT [pos][152] bf16 ----
  {
    int c = cch, strip = tid >> 7;             // 2 rows per thread
#pragma unroll
    for (int j = 0; j < 2; j++) {
      int h = strip * 2 + j;
      float acc[16];
#pragma unroll
      for (int w = 0; w < 16; w++) acc[w] = cb;
#pragma unroll
      for (int rr = 0; rr < 3; rr++) {
        int rg = h - 1 + rr;
        if (rg < 0 || rg > 15) continue;
        short8v s0 = *(const short8v*)&sY[c * 280 + rg * 16];
        short8v s1 = *(const short8v*)&sY[c * 280 + rg * 16 + 8];
        float f[18];
        f[0] = 0.f; f[17] = 0.f;
#pragma unroll
        for (int i = 0; i < 8; i++) { f[1 + i] = bf2f(s0[i]); f[9 + i] = bf2f(s1[i]); }
        float w0 = w_[rr * 3], w1 = w_[rr * 3 + 1], w2 = w_[rr * 3 + 2];
#pragma unroll
        for (int w = 0; w < 16; w++)
          acc[w] += w0 * f[w] + w1 * f[w + 1] + w2 * f[w + 2];
      }
#pragma unroll
      for (int w = 0; w < 16; w++)
        sT[(h * 16 + w) * 152 + c] = f2bf_s(acc[w]);
    }
  }
  __syncthreads();

  // ---- drop prefetched weights into sY region ----
  {
    uint4* wdst = (uint4*)pw_lds;
    wdst[tid] = pf0; wdst[tid + 1024] = pf1;
    if (tid < 992) wdst[tid + 2048] = pf2;
  }
  __syncthreads();

  // ---- fpw MFMA: r[o=128][pos=256], K=128; wave tile 32x64 ----
  int o0 = (wid & 3) * 32, pos0 = (wid >> 2) * 64;
  f32x4 facc[2][4] = {};
#pragma unroll
  for (int kk = 0; kk < 4; kk++) {
    int k0 = kk * 32 + kg * 8;
    short8v a0 = *(const short8v*)&pw_lds[(o0 + row) * 152 + k0];
    short8v a1 = *(const short8v*)&pw_lds[(o0 + 16 + row) * 152 + k0];
    short8v bb[4];
#pragma unroll
    for (int ni = 0; ni < 4; ni++)
      bb[ni] = *(const short8v*)&sT[(pos0 + ni * 16 + row) * 152 + k0];
#pragma unroll
    for (int ni = 0; ni < 4; ni++) {
      facc[0][ni] = __builtin_amdgcn_mfma_f32_16x16x32_bf16(a0, bb[ni], facc[0][ni], 0, 0, 0);
      facc[1][ni] = __builtin_amdgcn_mfma_f32_16x16x32_bf16(a1, bb[ni], facc[1][ni], 0, 0, 0);
    }
  }
  __syncthreads();

  // ---- bias + ReLU -> sT[pos][o] (overwrite) ----
#pragma unroll
  for (int mi = 0; mi < 2; mi++) {
    int ob = o0 + mi * 16 + kg * 4;
    float pb0 = pwbias[ob], pb1 = pwbias[ob + 1];
    float pb2 = pwbias[ob + 2], pb3 = pwbias[ob + 3];
#pragma unroll
    for (int ni = 0; ni < 4; ni++) {
      int pos = pos0 + ni * 16 + row;
      short4v pk;
      pk.x = f2bf_s(fmaxf(facc[mi][ni][0] + pb0, 0.f));
      pk.y = f2bf_s(fmaxf(facc[mi][ni][1] + pb1, 0.f));
      pk.z = f2bf_s(fmaxf(facc[mi][ni][2] + pb2, 0.f));
      pk.w = f2bf_s(fmaxf(facc[mi][ni][3] + pb3, 0.f));
      *(short4v*)&sT[pos * 152 + ob] = pk;
    }
  }
  __syncthreads();

  // ---- f2 MFMA: out[d=32][pos=256], K=128; direct residual store ----
  {
    f32x4 acc2[2] = {};
    int pos = wid * 16 + row;
#pragma unroll
    for (int kk = 0; kk < 4; kk++) {
      int k0 = kk * 32 + kg * 8;
      short8v a0 = *(const short8v*)&f2w_lds[row * 152 + k0];
      short8v a1 = *(const short8v*)&f2w_lds[(16 + row) * 152 + k0];
      short8v bb = *(const short8v*)&sT[pos * 152 + k0];
      acc2[0] = __builtin_amdgcn_mfma_f32_16x16x32_bf16(a0, bb, acc2[0], 0, 0, 0);
      acc2[1] = __builtin_amdgcn_mfma_f32_16x16x32_bf16(a1, bb, acc2[1], 0, 0, 0);
    }
#pragma unroll
    for (int mi = 0; mi < 2; mi++)
#pragma unroll
      for (int r2 = 0; r2 < 4; r2++) {
        int d = mi * 16 + kg * 4 + r2;
        xo[wid * 512 + mi * 256 + kg * 64 + r2 * 16 + row] =
            xr[mi][r2] + acc2[mi][r2] + f2b[d];
      }
  }
}

extern "C" void kernel_launch(void* const* d_in, const int* in_sizes, int n_in,
                              void* d_out, int out_size, void* d_ws, size_t ws_size,
                              hipStream_t stream) {
  const float* x_in   = (const float*)d_in[0];
  const float* ln1_g  = (const float*)d_in[1];
  const float* ln1_b  = (const float*)d_in[2];
  const float* ln2_g  = (const float*)d_in[3];
  const float* ln2_b  = (const float*)d_in[4];
  const float* qkv_dw = (const float*)d_in[5];
  const float* qkv_bng = (const float*)d_in[6];
  const float* qkv_bnb = (const float*)d_in[7];
  const float* qkv_bnm = (const float*)d_in[8];
  const float* qkv_bnv = (const float*)d_in[9];
  const float* qkv_pw = (const float*)d_in[10];
  const float* position = (const float*)d_in[11];
  const float* c1d_w  = (const float*)d_in[12];
  const float* c1d_b  = (const float*)d_in[13];
  const float* lin_w  = (const float*)d_in[14];
  const float* lin_b  = (const float*)d_in[15];
  const float* f1_w   = (const float*)d_in[16];
  const float* f1_b   = (const float*)d_in[17];
  const float* fdw_w  = (const float*)d_in[18];
  const float* fdw_b  = (const float*)d_in[19];
  const float* f_bng  = (const float*)d_in[20];
  const float* f_bnb  = (const float*)d_in[21];
  const float* f_bnm  = (const float*)d_in[22];
  const float* f_bnv  = (const float*)d_in[23];
  const float* fpw_w  = (const float*)d_in[24];
  const float* fpw_b  = (const float*)d_in[25];
  const float* f2_w   = (const float*)d_in[26];
  const float* f2_b   = (const float*)d_in[27];

  float* xbuf = (float*)d_out;                 // running x lives in d_out
  short* qkvA = (short*)d_ws;                  // 7680
  short* linb = qkvA + 7680;                   // 262144
  short* f1wb = linb + 262144;                 // 10240
  short* img  = f1wb + 10240;                  // 48640
  float* convW = (float*)(img + 48640);        // 2304
  float* convB = convW + 2304;                 // 256

  k_prep<<<1024, 256, 0, stream>>>(f1_w, fpw_w, f2_w, qkv_pw, lin_w,
      fdw_w, fdw_b, f_bng, f_bnb, f_bnm, f_bnv,
      qkvA, linb, f1wb, img, convW, convB);
  for (int l = 0; l < 2; l++) {
    const float* xin = (l == 0) ? x_in : xbuf;
    k_att<<<B_, 512, 0, stream>>>(xin, ln1_g + l * 512, ln1_b + l * 512,
        qkv_dw + l * 864, qkv_bng + l * 96, qkv_bnb + l * 96,
        qkv_bnm + l * 96, qkv_bnv + l * 96, qkvA + l * 3840,
        position + l * 1024, c1d_w + l * 128, c1d_b + l * 16,
        linb + l * 131072, lin_b + l * 512, xbuf);
    k_ffn4<<<B_, 1024, 0, stream>>>(xbuf, ln2_g + l * 512, ln2_b + l * 512,
        f1wb + l * 5120, f1_b + l * 128, convW + l * 1152, convB + l * 128,
        img + l * 24320, fpw_b + l * 128, f2_b + l * 32, xbuf);
  }
}